// Round 1
// baseline (2116.918 us; speedup 1.0000x reference)
//
#include <hip/hip_runtime.h>
#include <hip/hip_bf16.h>

#define B_    2
#define L_    2048
#define DM_   1024
#define DI_   2048
#define DS_   16
#define DTR_  64

// ---------------------------------------------------------------------------
// Generic 64x64x16 fp32 tiled GEMM.
//   C[m][n] = sum_k a(m,k) * b(n,k)
//   AMODE 0: a(m,k) = A[m*lda + k]   (K-contiguous)
//   AMODE 1: a(m,k) = A[k*lda + m]   (M-contiguous)
//   BMODE 0: b(n,k) = B[n*ldb + k]   (K-contiguous)
//   BMODE 1: b(n,k) = B[k*ldb + n]   (N-contiguous)
// N and K must be multiples of 64/16; M may be ragged (guarded).
// blockIdx.z = batch, with element strides sA/sB_/sC.
// ---------------------------------------------------------------------------
template<int AMODE, int BMODE>
__global__ __launch_bounds__(256) void gemm64(
    const float* __restrict__ A, const float* __restrict__ B,
    float* __restrict__ C,
    int M, int N, int K, int lda, int ldb, int ldc,
    long long sA, long long sB_, long long sC)
{
  constexpr int BM = 64, BN = 64, BK = 16;
  __shared__ float As[BK][BM + 4];
  __shared__ float Bs[BK][BN + 4];

  const int tid = threadIdx.x;
  const int bz  = blockIdx.z;
  A += sA  * bz;
  B += sB_ * bz;
  C += sC  * bz;

  const int m0 = blockIdx.y * BM;
  const int n0 = blockIdx.x * BN;
  const int tx = tid & 15;     // 16 cols of 4
  const int ty = tid >> 4;     // 16 rows of 4

  float acc[4][4] = {};

  for (int k0 = 0; k0 < K; k0 += BK) {
    // ---- load A tile (64x16 = 1024 elems, 4 per thread) ----
    #pragma unroll
    for (int i = 0; i < 4; ++i) {
      int idx = tid + i * 256;
      int m, k;
      if (AMODE == 0) { k = idx & (BK - 1); m = idx >> 4; }
      else            { m = idx & (BM - 1); k = idx >> 6; }
      int gm = m0 + m;
      float v = 0.f;
      if (gm < M)
        v = (AMODE == 0) ? A[(long long)gm * lda + (k0 + k)]
                         : A[(long long)(k0 + k) * lda + gm];
      As[k][m] = v;
    }
    // ---- load B tile ----
    #pragma unroll
    for (int i = 0; i < 4; ++i) {
      int idx = tid + i * 256;
      int n, k;
      if (BMODE == 0) { k = idx & (BK - 1); n = idx >> 4; }
      else            { n = idx & (BN - 1); k = idx >> 6; }
      int gn = n0 + n;
      float v = (BMODE == 0) ? B[(long long)gn * ldb + (k0 + k)]
                             : B[(long long)(k0 + k) * ldb + gn];
      Bs[k][n] = v;
    }
    __syncthreads();

    #pragma unroll
    for (int k = 0; k < BK; ++k) {
      float4 av = *(const float4*)&As[k][ty * 4];
      float4 bv = *(const float4*)&Bs[k][tx * 4];
      float a_[4] = {av.x, av.y, av.z, av.w};
      float b_[4] = {bv.x, bv.y, bv.z, bv.w};
      #pragma unroll
      for (int i = 0; i < 4; ++i)
        #pragma unroll
        for (int j = 0; j < 4; ++j)
          acc[i][j] = fmaf(a_[i], b_[j], acc[i][j]);
    }
    __syncthreads();
  }

  #pragma unroll
  for (int i = 0; i < 4; ++i) {
    int gm = m0 + ty * 4 + i;
    if (gm < M) {
      #pragma unroll
      for (int j = 0; j < 4; ++j)
        C[(long long)gm * ldc + n0 + tx * 4 + j] = acc[i][j];
    }
  }
}

// ---------------------------------------------------------------------------
// Depthwise causal conv (k=4) + bias + SiLU.
// in  : x half of xz, layout (B, 2*DI, L) rows 0..DI-1
// out : xconv (B, DI, L)
// One thread -> 4 consecutive l.
// ---------------------------------------------------------------------------
__global__ __launch_bounds__(256) void conv_silu_kernel(
    const float* __restrict__ xz, const float* __restrict__ cw,
    const float* __restrict__ cb, float* __restrict__ xc)
{
  int idx = blockIdx.x * 256 + threadIdx.x;       // [0, B*DI*L/4)
  int l4  = (idx & (L_ / 4 - 1)) << 2;
  int row = idx >> 9;                              // / (L/4)
  int d   = row & (DI_ - 1);
  int b   = row >> 11;

  const float* in = xz + ((size_t)b * 2 * DI_ + d) * L_;
  float w0 = cw[d * 4 + 0], w1 = cw[d * 4 + 1];
  float w2 = cw[d * 4 + 2], w3 = cw[d * 4 + 3];
  float bias = cb[d];

  float o[4];
  #pragma unroll
  for (int j = 0; j < 4; ++j) {
    int l = l4 + j;
    float acc = bias + in[l] * w3;
    if (l >= 1) acc += in[l - 1] * w2;
    if (l >= 2) acc += in[l - 2] * w1;
    if (l >= 3) acc += in[l - 3] * w0;
    float sig = 1.f / (1.f + __expf(-acc));
    o[j] = acc * sig;
  }
  *(float4*)&xc[(size_t)row * L_ + l4] = *(float4*)o;
}

// ---------------------------------------------------------------------------
// Selective scan. 16 lanes per (b,d): lane n owns state n.
// Reads delta_raw from x-half of xz (written by delta GEMM), z from z-half,
// x from xconv, B/C rows from x_dbl. Writes gated y in place over delta row.
// Block = 256 threads = 16 groups; 16 consecutive d, same b.
// Chunks of 64 l staged through LDS.
// ---------------------------------------------------------------------------
__global__ __launch_bounds__(256) void scan_kernel(
    float* __restrict__ xz, const float* __restrict__ xconv,
    const float* __restrict__ x_dbl, const float* __restrict__ A_log,
    const float* __restrict__ dtb, const float* __restrict__ Dw)
{
  const int tid = threadIdx.x;
  const int g   = tid >> 4;          // group within block
  const int n   = tid & 15;          // state index
  const int gid = blockIdx.x * 16 + g;
  const int b   = gid >> 11;
  const int d   = gid & (DI_ - 1);
  const int bb  = blockIdx.x >> 7;   // block-level batch
  const int d0  = (blockIdx.x << 4) & (DI_ - 1);

  const float An    = -expf(A_log[d * DS_ + n]);
  const float dtb_d = dtb[d];
  const float Dd    = Dw[d];

  float*       xrow  = xz + ((size_t)b * 2 * DI_ + d) * L_;          // delta in / y out
  const float* Bbase = x_dbl + ((size_t)b * 96 + DTR_) * L_;
  const float* Cbase = x_dbl + ((size_t)b * 96 + DTR_ + DS_) * L_;

  const float* drow0 = xz    + ((size_t)bb * 2 * DI_ + d0) * L_;
  const float* zrow0 = xz    + ((size_t)bb * 2 * DI_ + DI_ + d0) * L_;
  const float* xrow0 = xconv + ((size_t)bb * DI_ + d0) * L_;

  __shared__ float sD[16][65], sX[16][65], sZ[16][65];
  __shared__ float sB[64][17], sC[64][17];

  float h = 0.f;
  for (int l0 = 0; l0 < L_; l0 += 64) {
    __syncthreads();
    // stage B/C chunk: [l][n]
    #pragma unroll
    for (int i = 0; i < 4; ++i) {
      int idx = tid + i * 256;
      int nn = idx >> 6, ll = idx & 63;
      sB[ll][nn] = Bbase[(size_t)nn * L_ + l0 + ll];
      sC[ll][nn] = Cbase[(size_t)nn * L_ + l0 + ll];
    }
    // stage per-group rows: delta / x / z
    #pragma unroll
    for (int i = 0; i < 4; ++i) {
      int idx = tid + i * 256;
      int r = idx >> 6, ll = idx & 63;
      sD[r][ll] = drow0[(size_t)r * L_ + l0 + ll];
      sX[r][ll] = xrow0[(size_t)r * L_ + l0 + ll];
      sZ[r][ll] = zrow0[(size_t)r * L_ + l0 + ll];
    }
    __syncthreads();

    #pragma unroll 4
    for (int l = 0; l < 64; ++l) {
      float draw = sD[g][l] + dtb_d;
      float dv   = (draw > 20.f) ? draw : log1pf(__expf(draw));
      float xv   = sX[g][l];
      float zv   = sZ[g][l];
      float Bn   = sB[l][n];
      float Cn   = sC[l][n];

      float dA = __expf(dv * An);
      h = fmaf(dA, h, dv * Bn * xv);

      float p = h * Cn;
      p += __shfl_xor(p, 1, 16);
      p += __shfl_xor(p, 2, 16);
      p += __shfl_xor(p, 4, 16);
      p += __shfl_xor(p, 8, 16);

      if (n == 0) {
        float y   = p + xv * Dd;
        float sig = 1.f / (1.f + __expf(-zv));
        xrow[l0 + l] = y * zv * sig;
      }
    }
  }
}

// ---------------------------------------------------------------------------
extern "C" void kernel_launch(void* const* d_in, const int* in_sizes, int n_in,
                              void* d_out, int out_size, void* d_ws, size_t ws_size,
                              hipStream_t stream)
{
  const float* hs   = (const float*)d_in[0];  // (B, L, DM)
  const float* w1   = (const float*)d_in[1];  // (2*DI, DM)
  const float* cw   = (const float*)d_in[2];  // (DI, 1, 4)
  const float* cb   = (const float*)d_in[3];  // (DI,)
  const float* xpw  = (const float*)d_in[4];  // (96, DI)
  const float* dtw  = (const float*)d_in[5];  // (DI, 64)
  const float* dtbp = (const float*)d_in[6];  // (DI,)
  const float* Alog = (const float*)d_in[7];  // (DI, 16)
  const float* Dw   = (const float*)d_in[8];  // (DI,)
  const float* wo   = (const float*)d_in[9];  // (DM, DI)
  float* out = (float*)d_out;

  char* ws = (char*)d_ws;
  float* xz    = (float*)ws;                                     // B*2DI*L  (67 MB)
  float* xconv = (float*)(ws + (size_t)B_ * 2 * DI_ * L_ * 4);   // B*DI*L   (33.5 MB)
  float* xdbl  = (float*)(ws + (size_t)B_ * 2 * DI_ * L_ * 4
                             + (size_t)B_ * DI_ * L_ * 4);       // B*96*L   (1.6 MB)

  // K1: xz[b][e][l] = sum_d hs[b][l][d] * w1[e][d]
  {
    dim3 g(L_ / 64, (2 * DI_) / 64, B_);
    gemm64<0, 0><<<g, 256, 0, stream>>>(w1, hs, xz,
        2 * DI_, L_, DM_, DM_, DM_, L_,
        0LL, (long long)L_ * DM_, (long long)2 * DI_ * L_);
  }

  // K2: depthwise conv + SiLU
  conv_silu_kernel<<<dim3(B_ * DI_ * L_ / 4 / 256), 256, 0, stream>>>(xz, cw, cb, xconv);

  // K3: x_dbl[b][k][l] = sum_d xpw[k][d] * xconv[b][d][l]   (M=96 ragged)
  {
    dim3 g(L_ / 64, 2, B_);
    gemm64<0, 1><<<g, 256, 0, stream>>>(xpw, xconv, xdbl,
        96, L_, DI_, DI_, L_, L_,
        0LL, (long long)DI_ * L_, (long long)96 * L_);
  }

  // K4: delta_raw[b][d][l] = sum_r dtw[d][r] * x_dbl[b][r][l] -> x-half of xz
  {
    dim3 g(L_ / 64, DI_ / 64, B_);
    gemm64<0, 1><<<g, 256, 0, stream>>>(dtw, xdbl, xz,
        DI_, L_, DTR_, DTR_, L_, L_,
        0LL, (long long)96 * L_, (long long)2 * DI_ * L_);
  }

  // K5: selective scan (+ D skip, SiLU(z) gate). y overwrites delta rows.
  scan_kernel<<<dim3(B_ * DI_ / 16), 256, 0, stream>>>(xz, xconv, xdbl, Alog, dtbp, Dw);

  // K6: out[b][l][o] = sum_d y[b][d][l] * wo[o][d]
  {
    dim3 g(DM_ / 64, L_ / 64, B_);
    gemm64<1, 0><<<g, 256, 0, stream>>>(xz, wo, out,
        L_, DM_, DI_, L_, DI_, DM_,
        (long long)2 * DI_ * L_, 0LL, (long long)L_ * DM_);
  }
}

// Round 4
// 1539.589 us; speedup vs baseline: 1.3750x; 1.3750x over previous
//
#include <hip/hip_runtime.h>
#include <hip/hip_bf16.h>

#define B_    2
#define L_    2048
#define DM_   1024
#define DI_   2048
#define DS_   16
#define DTR_  64

typedef __bf16 v8bf __attribute__((ext_vector_type(8)));
typedef float  v4f  __attribute__((ext_vector_type(4)));
typedef unsigned short us8 __attribute__((ext_vector_type(8)));
typedef unsigned short us4 __attribute__((ext_vector_type(4)));

__device__ __forceinline__ unsigned short f2bf(float f) {
  union { float f; unsigned u; } v; v.f = f;
  unsigned r = v.u + 0x7FFFu + ((v.u >> 16) & 1u);
  return (unsigned short)(r >> 16);
}

// ---------------------------------------------------------------------------
// bf16 MFMA GEMM, 128x128 tile, BK=32, 4 waves (2x2), 16x16x32 MFMA.
//   C[m][n] = sum_k a(m,k)*b(n,k); A always row-major [M][K] (K-contig).
//   BCOL 0: b(n,k) = B[n*ldb + k]  (K-contig rows, row-staged)
//   BCOL 1: b(n,k) = B[k*ldb + n]  (N-contig, col-staged w/ reg transpose)
//   CT   0: C[m*ldc + n]    CT 1: C[n*ldc + m] (per-lane float4 over m)
// M,N multiples of 128; K multiple of 32. fp32 in/out, bf16 compute.
// LDS [128][32] bf16 rows (64B), XOR-swizzled: byte ^= ((row&7)<<4).
// ---------------------------------------------------------------------------
template<int BCOL, int CT>
__global__ __launch_bounds__(256) void gemm_mfma(
    const float* __restrict__ A, const float* __restrict__ B,
    float* __restrict__ C,
    int M, int N, int K, int lda, int ldb, int ldc,
    long long sA, long long sB_, long long sC)
{
  __shared__ unsigned short lA[128 * 32];
  __shared__ unsigned short lB[128 * 32];

  const int tid  = threadIdx.x;
  const int bz   = blockIdx.z;
  A += sA  * bz;
  B += sB_ * bz;
  C += sC  * bz;

  const int m0 = blockIdx.y * 128;
  const int n0 = blockIdx.x * 128;
  const int wave = tid >> 6, lane = tid & 63;
  const int wr = wave >> 1, wc = wave & 1;
  const int lrow = lane & 15, lk = lane >> 4;   // frag row / k-chunk

  v4f acc[4][4];
  #pragma unroll
  for (int i = 0; i < 4; ++i)
    #pragma unroll
    for (int j = 0; j < 4; ++j) acc[i][j] = (v4f)0.f;

  const int sr  = tid >> 1, skh = (tid & 1) * 16;   // row staging
  const int cn4 = (tid & 31) * 4, ck4 = (tid >> 5) * 4;  // col staging

  for (int k0 = 0; k0 < K; k0 += 32) {
    __syncthreads();
    // ---- A tile: row-staged ----
    {
      const float* src = A + (long long)(m0 + sr) * lda + k0 + skh;
      unsigned short tmp[16];
      #pragma unroll
      for (int q = 0; q < 4; ++q) {
        float4 v = *(const float4*)(src + q * 4);
        tmp[q*4+0] = f2bf(v.x); tmp[q*4+1] = f2bf(v.y);
        tmp[q*4+2] = f2bf(v.z); tmp[q*4+3] = f2bf(v.w);
      }
      int b0 = sr * 64 + skh * 2;
      int sw = (sr & 7) << 4;
      *(us8*)((char*)lA + ((b0)      ^ sw)) = *(us8*)tmp;
      *(us8*)((char*)lA + ((b0 + 16) ^ sw)) = *(us8*)(tmp + 8);
    }
    // ---- B tile ----
    if (BCOL == 0) {
      const float* src = B + (long long)(n0 + sr) * ldb + k0 + skh;
      unsigned short tmp[16];
      #pragma unroll
      for (int q = 0; q < 4; ++q) {
        float4 v = *(const float4*)(src + q * 4);
        tmp[q*4+0] = f2bf(v.x); tmp[q*4+1] = f2bf(v.y);
        tmp[q*4+2] = f2bf(v.z); tmp[q*4+3] = f2bf(v.w);
      }
      int b0 = sr * 64 + skh * 2;
      int sw = (sr & 7) << 4;
      *(us8*)((char*)lB + ((b0)      ^ sw)) = *(us8*)tmp;
      *(us8*)((char*)lB + ((b0 + 16) ^ sw)) = *(us8*)(tmp + 8);
    } else {
      float va[4][4];
      #pragma unroll
      for (int kk = 0; kk < 4; ++kk) {
        float4 v = *(const float4*)(B + (long long)(k0 + ck4 + kk) * ldb + n0 + cn4);
        va[kk][0] = v.x; va[kk][1] = v.y; va[kk][2] = v.z; va[kk][3] = v.w;
      }
      #pragma unroll
      for (int nn = 0; nn < 4; ++nn) {
        us4 w;
        w[0] = f2bf(va[0][nn]); w[1] = f2bf(va[1][nn]);
        w[2] = f2bf(va[2][nn]); w[3] = f2bf(va[3][nn]);
        int row = cn4 + nn;
        int b0  = row * 64 + ck4 * 2;
        *(us4*)((char*)lB + (b0 ^ ((row & 7) << 4))) = w;
      }
    }
    __syncthreads();

    // ---- fragments + MFMA ----
    v8bf af[4], bf[4];
    #pragma unroll
    for (int i = 0; i < 4; ++i) {
      int r  = wr * 64 + i * 16 + lrow;
      int b0 = (r * 64 + lk * 16) ^ ((r & 7) << 4);
      af[i] = __builtin_bit_cast(v8bf, *(const us8*)((const char*)lA + b0));
    }
    #pragma unroll
    for (int j = 0; j < 4; ++j) {
      int r  = wc * 64 + j * 16 + lrow;
      int b0 = (r * 64 + lk * 16) ^ ((r & 7) << 4);
      bf[j] = __builtin_bit_cast(v8bf, *(const us8*)((const char*)lB + b0));
    }
    #pragma unroll
    for (int i = 0; i < 4; ++i)
      #pragma unroll
      for (int j = 0; j < 4; ++j)
        acc[i][j] = __builtin_amdgcn_mfma_f32_16x16x32_bf16(af[i], bf[j], acc[i][j], 0, 0, 0);
  }

  // ---- epilogue ----
  #pragma unroll
  for (int i = 0; i < 4; ++i) {
    #pragma unroll
    for (int j = 0; j < 4; ++j) {
      int gm = m0 + wr * 64 + i * 16 + lk * 4;
      int gn = n0 + wc * 64 + j * 16 + lrow;
      if (CT == 0) {
        #pragma unroll
        for (int r = 0; r < 4; ++r)
          C[(long long)(gm + r) * ldc + gn] = acc[i][j][r];
      } else {
        *(v4f*)&C[(long long)gn * ldc + gm] = acc[i][j];
      }
    }
  }
}

// ---------------------------------------------------------------------------
// Generic 64x64x16 fp32 tiled GEMM (round-1 exact).
// ---------------------------------------------------------------------------
template<int AMODE, int BMODE>
__global__ __launch_bounds__(256) void gemm64(
    const float* __restrict__ A, const float* __restrict__ B,
    float* __restrict__ C,
    int M, int N, int K, int lda, int ldb, int ldc,
    long long sA, long long sB_, long long sC)
{
  constexpr int BM = 64, BN = 64, BK = 16;
  __shared__ float As[BK][BM + 4];
  __shared__ float Bs[BK][BN + 4];

  const int tid = threadIdx.x;
  const int bz  = blockIdx.z;
  A += sA  * bz;
  B += sB_ * bz;
  C += sC  * bz;

  const int m0 = blockIdx.y * BM;
  const int n0 = blockIdx.x * BN;
  const int tx = tid & 15;
  const int ty = tid >> 4;

  float acc[4][4] = {};

  for (int k0 = 0; k0 < K; k0 += BK) {
    #pragma unroll
    for (int i = 0; i < 4; ++i) {
      int idx = tid + i * 256;
      int m, k;
      if (AMODE == 0) { k = idx & (BK - 1); m = idx >> 4; }
      else            { m = idx & (BM - 1); k = idx >> 6; }
      int gm = m0 + m;
      float v = 0.f;
      if (gm < M)
        v = (AMODE == 0) ? A[(long long)gm * lda + (k0 + k)]
                         : A[(long long)(k0 + k) * lda + gm];
      As[k][m] = v;
    }
    #pragma unroll
    for (int i = 0; i < 4; ++i) {
      int idx = tid + i * 256;
      int n, k;
      if (BMODE == 0) { k = idx & (BK - 1); n = idx >> 4; }
      else            { n = idx & (BN - 1); k = idx >> 6; }
      int gn = n0 + n;
      float v = (BMODE == 0) ? B[(long long)gn * ldb + (k0 + k)]
                             : B[(long long)(k0 + k) * ldb + gn];
      Bs[k][n] = v;
    }
    __syncthreads();

    #pragma unroll
    for (int k = 0; k < BK; ++k) {
      float4 av = *(const float4*)&As[k][ty * 4];
      float4 bv = *(const float4*)&Bs[k][tx * 4];
      float a_[4] = {av.x, av.y, av.z, av.w};
      float b_[4] = {bv.x, bv.y, bv.z, bv.w};
      #pragma unroll
      for (int i = 0; i < 4; ++i)
        #pragma unroll
        for (int j = 0; j < 4; ++j)
          acc[i][j] = fmaf(a_[i], b_[j], acc[i][j]);
    }
    __syncthreads();
  }

  #pragma unroll
  for (int i = 0; i < 4; ++i) {
    int gm = m0 + ty * 4 + i;
    if (gm < M) {
      #pragma unroll
      for (int j = 0; j < 4; ++j)
        C[(long long)gm * ldc + n0 + tx * 4 + j] = acc[i][j];
    }
  }
}

// ---------------------------------------------------------------------------
// Depthwise causal conv (k=4) + bias + SiLU (round-1 exact).
// ---------------------------------------------------------------------------
__global__ __launch_bounds__(256) void conv_silu_kernel(
    const float* __restrict__ xz, const float* __restrict__ cw,
    const float* __restrict__ cb, float* __restrict__ xc)
{
  int idx = blockIdx.x * 256 + threadIdx.x;
  int l4  = (idx & (L_ / 4 - 1)) << 2;
  int row = idx >> 9;
  int d   = row & (DI_ - 1);
  int b   = row >> 11;

  const float* in = xz + ((size_t)b * 2 * DI_ + d) * L_;
  float w0 = cw[d * 4 + 0], w1 = cw[d * 4 + 1];
  float w2 = cw[d * 4 + 2], w3 = cw[d * 4 + 3];
  float bias = cb[d];

  float o[4];
  #pragma unroll
  for (int j = 0; j < 4; ++j) {
    int l = l4 + j;
    float acc = bias + in[l] * w3;
    if (l >= 1) acc += in[l - 1] * w2;
    if (l >= 2) acc += in[l - 2] * w1;
    if (l >= 3) acc += in[l - 3] * w0;
    float sig = 1.f / (1.f + __expf(-acc));
    o[j] = acc * sig;
  }
  *(float4*)&xc[(size_t)row * L_ + l4] = *(float4*)o;
}

// ---------------------------------------------------------------------------
// Selective scan (round-1 exact; replay-stable).
// ---------------------------------------------------------------------------
__global__ __launch_bounds__(256) void scan_kernel(
    float* __restrict__ xz, const float* __restrict__ xconv,
    const float* __restrict__ x_dbl, const float* __restrict__ A_log,
    const float* __restrict__ dtb, const float* __restrict__ Dw)
{
  const int tid = threadIdx.x;
  const int g   = tid >> 4;
  const int n   = tid & 15;
  const int gid = blockIdx.x * 16 + g;
  const int b   = gid >> 11;
  const int d   = gid & (DI_ - 1);
  const int bb  = blockIdx.x >> 7;
  const int d0  = (blockIdx.x << 4) & (DI_ - 1);

  const float An    = -expf(A_log[d * DS_ + n]);
  const float dtb_d = dtb[d];
  const float Dd    = Dw[d];

  float*       xrow  = xz + ((size_t)b * 2 * DI_ + d) * L_;
  const float* Bbase = x_dbl + ((size_t)b * 96 + DTR_) * L_;
  const float* Cbase = x_dbl + ((size_t)b * 96 + DTR_ + DS_) * L_;

  const float* drow0 = xz    + ((size_t)bb * 2 * DI_ + d0) * L_;
  const float* zrow0 = xz    + ((size_t)bb * 2 * DI_ + DI_ + d0) * L_;
  const float* xrow0 = xconv + ((size_t)bb * DI_ + d0) * L_;

  __shared__ float sD[16][65], sX[16][65], sZ[16][65];
  __shared__ float sB[64][17], sC[64][17];

  float h = 0.f;
  for (int l0 = 0; l0 < L_; l0 += 64) {
    __syncthreads();
    #pragma unroll
    for (int i = 0; i < 4; ++i) {
      int idx = tid + i * 256;
      int nn = idx >> 6, ll = idx & 63;
      sB[ll][nn] = Bbase[(size_t)nn * L_ + l0 + ll];
      sC[ll][nn] = Cbase[(size_t)nn * L_ + l0 + ll];
    }
    #pragma unroll
    for (int i = 0; i < 4; ++i) {
      int idx = tid + i * 256;
      int r = idx >> 6, ll = idx & 63;
      sD[r][ll] = drow0[(size_t)r * L_ + l0 + ll];
      sX[r][ll] = xrow0[(size_t)r * L_ + l0 + ll];
      sZ[r][ll] = zrow0[(size_t)r * L_ + l0 + ll];
    }
    __syncthreads();

    #pragma unroll 4
    for (int l = 0; l < 64; ++l) {
      float draw = sD[g][l] + dtb_d;
      float dv   = (draw > 20.f) ? draw : log1pf(__expf(draw));
      float xv   = sX[g][l];
      float zv   = sZ[g][l];
      float Bn   = sB[l][n];
      float Cn   = sC[l][n];

      float dA = __expf(dv * An);
      h = fmaf(dA, h, dv * Bn * xv);

      float p = h * Cn;
      p += __shfl_xor(p, 1, 16);
      p += __shfl_xor(p, 2, 16);
      p += __shfl_xor(p, 4, 16);
      p += __shfl_xor(p, 8, 16);

      if (n == 0) {
        float y   = p + xv * Dd;
        float sig = 1.f / (1.f + __expf(-zv));
        xrow[l0 + l] = y * zv * sig;
      }
    }
  }
}

// ---------------------------------------------------------------------------
extern "C" void kernel_launch(void* const* d_in, const int* in_sizes, int n_in,
                              void* d_out, int out_size, void* d_ws, size_t ws_size,
                              hipStream_t stream)
{
  const float* hs   = (const float*)d_in[0];
  const float* w1   = (const float*)d_in[1];
  const float* cw   = (const float*)d_in[2];
  const float* cb   = (const float*)d_in[3];
  const float* xpw  = (const float*)d_in[4];
  const float* dtw  = (const float*)d_in[5];
  const float* dtbp = (const float*)d_in[6];
  const float* Alog = (const float*)d_in[7];
  const float* Dw   = (const float*)d_in[8];
  const float* wo   = (const float*)d_in[9];
  float* out = (float*)d_out;

  char* ws = (char*)d_ws;
  float* xz    = (float*)ws;                                     // B*2DI*L
  float* xconv = (float*)(ws + (size_t)B_ * 2 * DI_ * L_ * 4);   // B*DI*L
  float* xdbl  = (float*)(ws + (size_t)B_ * 2 * DI_ * L_ * 4
                             + (size_t)B_ * DI_ * L_ * 4);       // B*96*L

  // K1 (bf16 MFMA): xz[b][e][l] = sum_d hs[b][l][d] * w1[e][d]
  {
    dim3 g(L_ / 128, (2 * DI_) / 128, B_);
    gemm_mfma<0, 0><<<g, 256, 0, stream>>>(w1, hs, xz,
        2 * DI_, L_, DM_, DM_, DM_, L_,
        0LL, (long long)L_ * DM_, (long long)2 * DI_ * L_);
  }

  // K2: depthwise conv + SiLU
  conv_silu_kernel<<<dim3(B_ * DI_ * L_ / 4 / 256), 256, 0, stream>>>(xz, cw, cb, xconv);

  // K3: x_dbl[b][k][l] = sum_d xpw[k][d] * xconv[b][d][l]
  {
    dim3 g(L_ / 64, 2, B_);
    gemm64<0, 1><<<g, 256, 0, stream>>>(xpw, xconv, xdbl,
        96, L_, DI_, DI_, L_, L_,
        0LL, (long long)DI_ * L_, (long long)96 * L_);
  }

  // K4: delta_raw[b][d][l] = sum_r dtw[d][r] * x_dbl[b][r][l] -> x-half of xz
  {
    dim3 g(L_ / 64, DI_ / 64, B_);
    gemm64<0, 1><<<g, 256, 0, stream>>>(dtw, xdbl, xz,
        DI_, L_, DTR_, DTR_, L_, L_,
        0LL, (long long)96 * L_, (long long)2 * DI_ * L_);
  }

  // K5: selective scan (round-1 serial, replay-stable)
  scan_kernel<<<dim3(B_ * DI_ / 16), 256, 0, stream>>>(xz, xconv, xdbl, Alog, dtbp, Dw);

  // K6 (bf16 MFMA, M=o): out[b][l][o] = sum_d y[b][d][l] * wo[o][d]
  {
    dim3 g(L_ / 128, DM_ / 128, B_);
    gemm_mfma<1, 1><<<g, 256, 0, stream>>>(wo, xz, out,
        DM_, L_, DI_, DI_, L_, DM_,
        0LL, (long long)2 * DI_ * L_, (long long)L_ * DM_);
  }
}

// Round 6
// 698.356 us; speedup vs baseline: 3.0313x; 2.2046x over previous
//
#include <hip/hip_runtime.h>
#include <hip/hip_bf16.h>

#define B_    2
#define L_    2048
#define DM_   1024
#define DI_   2048
#define DS_   16
#define DTR_  64

typedef __bf16 v8bf __attribute__((ext_vector_type(8)));
typedef float  v4f  __attribute__((ext_vector_type(4)));
typedef unsigned short us8 __attribute__((ext_vector_type(8)));
typedef unsigned short us4 __attribute__((ext_vector_type(4)));

__device__ __forceinline__ unsigned short f2bf(float f) {
  union { float f; unsigned u; } v; v.f = f;
  unsigned r = v.u + 0x7FFFu + ((v.u >> 16) & 1u);
  return (unsigned short)(r >> 16);
}

// DPP row_shr reduction step: p += lane(p - SHIFT) within 16-lane row.
// row_shr:N ctrl = 0x110 | N; out-of-row reads 0 (bound_ctrl=true).
// After shifts 1,2,4,8 the FULL row sum lands in lane 15 of each row.
template<int CTRL>
__device__ __forceinline__ float dpp_shr_add(float x) {
  int xi = __builtin_bit_cast(int, x);
  int yi = __builtin_amdgcn_update_dpp(xi, xi, CTRL, 0xF, 0xF, true);
  return x + __builtin_bit_cast(float, yi);
}

// ---------------------------------------------------------------------------
// bf16 MFMA GEMM, 128x128 tile, BK=32, 4 waves (2x2), 16x16x32 MFMA.
//   C[m][n] = sum_k a(m,k)*b(n,k); A always row-major [M][K] (K-contig).
//   BCOL 0: b(n,k) = B[n*ldb + k]  (K-contig rows, row-staged)
//   BCOL 1: b(n,k) = B[k*ldb + n]  (N-contig, col-staged w/ reg transpose)
//   CT   0: C[m*ldc + n]    CT 1: C[n*ldc + m] (per-lane float4 over m)
// ---------------------------------------------------------------------------
template<int BCOL, int CT>
__global__ __launch_bounds__(256) void gemm_mfma(
    const float* __restrict__ A, const float* __restrict__ B,
    float* __restrict__ C,
    int M, int N, int K, int lda, int ldb, int ldc,
    long long sA, long long sB_, long long sC)
{
  __shared__ unsigned short lA[128 * 32];
  __shared__ unsigned short lB[128 * 32];

  const int tid  = threadIdx.x;
  const int bz   = blockIdx.z;
  A += sA  * bz;
  B += sB_ * bz;
  C += sC  * bz;

  const int m0 = blockIdx.y * 128;
  const int n0 = blockIdx.x * 128;
  const int wave = tid >> 6, lane = tid & 63;
  const int wr = wave >> 1, wc = wave & 1;
  const int lrow = lane & 15, lk = lane >> 4;

  v4f acc[4][4];
  #pragma unroll
  for (int i = 0; i < 4; ++i)
    #pragma unroll
    for (int j = 0; j < 4; ++j) acc[i][j] = (v4f)0.f;

  const int sr  = tid >> 1, skh = (tid & 1) * 16;
  const int cn4 = (tid & 31) * 4, ck4 = (tid >> 5) * 4;

  for (int k0 = 0; k0 < K; k0 += 32) {
    __syncthreads();
    {
      const float* src = A + (long long)(m0 + sr) * lda + k0 + skh;
      unsigned short tmp[16];
      #pragma unroll
      for (int q = 0; q < 4; ++q) {
        float4 v = *(const float4*)(src + q * 4);
        tmp[q*4+0] = f2bf(v.x); tmp[q*4+1] = f2bf(v.y);
        tmp[q*4+2] = f2bf(v.z); tmp[q*4+3] = f2bf(v.w);
      }
      int b0 = sr * 64 + skh * 2;
      int sw = (sr & 7) << 4;
      *(us8*)((char*)lA + ((b0)      ^ sw)) = *(us8*)tmp;
      *(us8*)((char*)lA + ((b0 + 16) ^ sw)) = *(us8*)(tmp + 8);
    }
    if (BCOL == 0) {
      const float* src = B + (long long)(n0 + sr) * ldb + k0 + skh;
      unsigned short tmp[16];
      #pragma unroll
      for (int q = 0; q < 4; ++q) {
        float4 v = *(const float4*)(src + q * 4);
        tmp[q*4+0] = f2bf(v.x); tmp[q*4+1] = f2bf(v.y);
        tmp[q*4+2] = f2bf(v.z); tmp[q*4+3] = f2bf(v.w);
      }
      int b0 = sr * 64 + skh * 2;
      int sw = (sr & 7) << 4;
      *(us8*)((char*)lB + ((b0)      ^ sw)) = *(us8*)tmp;
      *(us8*)((char*)lB + ((b0 + 16) ^ sw)) = *(us8*)(tmp + 8);
    } else {
      float va[4][4];
      #pragma unroll
      for (int kk = 0; kk < 4; ++kk) {
        float4 v = *(const float4*)(B + (long long)(k0 + ck4 + kk) * ldb + n0 + cn4);
        va[kk][0] = v.x; va[kk][1] = v.y; va[kk][2] = v.z; va[kk][3] = v.w;
      }
      #pragma unroll
      for (int nn = 0; nn < 4; ++nn) {
        us4 w;
        w[0] = f2bf(va[0][nn]); w[1] = f2bf(va[1][nn]);
        w[2] = f2bf(va[2][nn]); w[3] = f2bf(va[3][nn]);
        int row = cn4 + nn;
        int b0  = row * 64 + ck4 * 2;
        *(us4*)((char*)lB + (b0 ^ ((row & 7) << 4))) = w;
      }
    }
    __syncthreads();

    v8bf af[4], bf[4];
    #pragma unroll
    for (int i = 0; i < 4; ++i) {
      int r  = wr * 64 + i * 16 + lrow;
      int b0 = (r * 64 + lk * 16) ^ ((r & 7) << 4);
      af[i] = __builtin_bit_cast(v8bf, *(const us8*)((const char*)lA + b0));
    }
    #pragma unroll
    for (int j = 0; j < 4; ++j) {
      int r  = wc * 64 + j * 16 + lrow;
      int b0 = (r * 64 + lk * 16) ^ ((r & 7) << 4);
      bf[j] = __builtin_bit_cast(v8bf, *(const us8*)((const char*)lB + b0));
    }
    #pragma unroll
    for (int i = 0; i < 4; ++i)
      #pragma unroll
      for (int j = 0; j < 4; ++j)
        acc[i][j] = __builtin_amdgcn_mfma_f32_16x16x32_bf16(af[i], bf[j], acc[i][j], 0, 0, 0);
  }

  #pragma unroll
  for (int i = 0; i < 4; ++i) {
    #pragma unroll
    for (int j = 0; j < 4; ++j) {
      int gm = m0 + wr * 64 + i * 16 + lk * 4;
      int gn = n0 + wc * 64 + j * 16 + lrow;
      if (CT == 0) {
        #pragma unroll
        for (int r = 0; r < 4; ++r)
          C[(long long)(gm + r) * ldc + gn] = acc[i][j][r];
      } else {
        *(v4f*)&C[(long long)gn * ldc + gm] = acc[i][j];
      }
    }
  }
}

// ---------------------------------------------------------------------------
// Generic 64x64x16 fp32 tiled GEMM (round-1 exact).
// ---------------------------------------------------------------------------
template<int AMODE, int BMODE>
__global__ __launch_bounds__(256) void gemm64(
    const float* __restrict__ A, const float* __restrict__ B,
    float* __restrict__ C,
    int M, int N, int K, int lda, int ldb, int ldc,
    long long sA, long long sB_, long long sC)
{
  constexpr int BM = 64, BN = 64, BK = 16;
  __shared__ float As[BK][BM + 4];
  __shared__ float Bs[BK][BN + 4];

  const int tid = threadIdx.x;
  const int bz  = blockIdx.z;
  A += sA  * bz;
  B += sB_ * bz;
  C += sC  * bz;

  const int m0 = blockIdx.y * BM;
  const int n0 = blockIdx.x * BN;
  const int tx = tid & 15;
  const int ty = tid >> 4;

  float acc[4][4] = {};

  for (int k0 = 0; k0 < K; k0 += BK) {
    #pragma unroll
    for (int i = 0; i < 4; ++i) {
      int idx = tid + i * 256;
      int m, k;
      if (AMODE == 0) { k = idx & (BK - 1); m = idx >> 4; }
      else            { m = idx & (BM - 1); k = idx >> 6; }
      int gm = m0 + m;
      float v = 0.f;
      if (gm < M)
        v = (AMODE == 0) ? A[(long long)gm * lda + (k0 + k)]
                         : A[(long long)(k0 + k) * lda + gm];
      As[k][m] = v;
    }
    #pragma unroll
    for (int i = 0; i < 4; ++i) {
      int idx = tid + i * 256;
      int n, k;
      if (BMODE == 0) { k = idx & (BK - 1); n = idx >> 4; }
      else            { n = idx & (BN - 1); k = idx >> 6; }
      int gn = n0 + n;
      float v = (BMODE == 0) ? B[(long long)gn * ldb + (k0 + k)]
                             : B[(long long)(k0 + k) * ldb + gn];
      Bs[k][n] = v;
    }
    __syncthreads();

    #pragma unroll
    for (int k = 0; k < BK; ++k) {
      float4 av = *(const float4*)&As[k][ty * 4];
      float4 bv = *(const float4*)&Bs[k][tx * 4];
      float a_[4] = {av.x, av.y, av.z, av.w};
      float b_[4] = {bv.x, bv.y, bv.z, bv.w};
      #pragma unroll
      for (int i = 0; i < 4; ++i)
        #pragma unroll
        for (int j = 0; j < 4; ++j)
          acc[i][j] = fmaf(a_[i], b_[j], acc[i][j]);
    }
    __syncthreads();
  }

  #pragma unroll
  for (int i = 0; i < 4; ++i) {
    int gm = m0 + ty * 4 + i;
    if (gm < M) {
      #pragma unroll
      for (int j = 0; j < 4; ++j)
        C[(long long)gm * ldc + n0 + tx * 4 + j] = acc[i][j];
    }
  }
}

// ---------------------------------------------------------------------------
// Depthwise causal conv (k=4) + bias + SiLU (round-1 exact).
// ---------------------------------------------------------------------------
__global__ __launch_bounds__(256) void conv_silu_kernel(
    const float* __restrict__ xz, const float* __restrict__ cw,
    const float* __restrict__ cb, float* __restrict__ xc)
{
  int idx = blockIdx.x * 256 + threadIdx.x;
  int l4  = (idx & (L_ / 4 - 1)) << 2;
  int row = idx >> 9;
  int d   = row & (DI_ - 1);
  int b   = row >> 11;

  const float* in = xz + ((size_t)b * 2 * DI_ + d) * L_;
  float w0 = cw[d * 4 + 0], w1 = cw[d * 4 + 1];
  float w2 = cw[d * 4 + 2], w3 = cw[d * 4 + 3];
  float bias = cb[d];

  float o[4];
  #pragma unroll
  for (int j = 0; j < 4; ++j) {
    int l = l4 + j;
    float acc = bias + in[l] * w3;
    if (l >= 1) acc += in[l - 1] * w2;
    if (l >= 2) acc += in[l - 2] * w1;
    if (l >= 3) acc += in[l - 3] * w0;
    float sig = 1.f / (1.f + __expf(-acc));
    o[j] = acc * sig;
  }
  *(float4*)&xc[(size_t)row * L_ + l4] = *(float4*)o;
}

// ---------------------------------------------------------------------------
// Selective scan v2: round-1 skeleton (one kernel, serial over L, 16 groups
// x 16 state-lanes per 256-thr block, in-place y over delta rows) but:
// 4 l-steps per iteration, ds_read_b128 LDS reads ([16][68] layout),
// DPP row_shr reduction (sum lands in lane n=15), fast softplus.
// ---------------------------------------------------------------------------
__global__ __launch_bounds__(256) void scan_kernel(
    float* __restrict__ xz, const float* __restrict__ xconv,
    const float* __restrict__ x_dbl, const float* __restrict__ A_log,
    const float* __restrict__ dtb, const float* __restrict__ Dw)
{
  const int tid = threadIdx.x;
  const int g   = tid >> 4;          // channel group within block
  const int n   = tid & 15;          // state lane
  const int gid = blockIdx.x * 16 + g;
  const int b   = gid >> 11;
  const int d   = gid & (DI_ - 1);
  const int bb  = blockIdx.x >> 7;
  const int d0  = (blockIdx.x << 4) & (DI_ - 1);

  const float An    = -expf(A_log[d * DS_ + n]);
  const float dtb_d = dtb[d];
  const float Dd    = Dw[d];

  float*       xrow  = xz + ((size_t)b * 2 * DI_ + d) * L_;          // y out
  const float* Bbase = x_dbl + ((size_t)b * 96 + DTR_) * L_;
  const float* Cbase = x_dbl + ((size_t)b * 96 + DTR_ + DS_) * L_;

  const float* drow0 = xz    + ((size_t)bb * 2 * DI_ + d0) * L_;
  const float* zrow0 = xz    + ((size_t)bb * 2 * DI_ + DI_ + d0) * L_;
  const float* xrow0 = xconv + ((size_t)bb * DI_ + d0) * L_;

  __shared__ float sD[16][68], sX[16][68], sZ[16][68];
  __shared__ float sB[16][68], sC[16][68];

  const int sr = tid >> 4, sc4 = (tid & 15) * 4;   // staging: row, col4

  float h = 0.f;
  for (int l0 = 0; l0 < L_; l0 += 64) {
    __syncthreads();
    // stage 5 arrays: each thread one float4 per array (coalesced 64B/16 lanes)
    *(float4*)&sD[sr][sc4] = *(const float4*)&drow0[(size_t)sr * L_ + l0 + sc4];
    *(float4*)&sX[sr][sc4] = *(const float4*)&xrow0[(size_t)sr * L_ + l0 + sc4];
    *(float4*)&sZ[sr][sc4] = *(const float4*)&zrow0[(size_t)sr * L_ + l0 + sc4];
    *(float4*)&sB[sr][sc4] = *(const float4*)&Bbase[(size_t)sr * L_ + l0 + sc4];
    *(float4*)&sC[sr][sc4] = *(const float4*)&Cbase[(size_t)sr * L_ + l0 + sc4];
    __syncthreads();

    #pragma unroll
    for (int l4 = 0; l4 < 64; l4 += 4) {
      float dv[4], xv[4], zv[4], Bn[4], Cn[4];
      *(float4*)dv = *(const float4*)&sD[g][l4];
      *(float4*)xv = *(const float4*)&sX[g][l4];
      *(float4*)zv = *(const float4*)&sZ[g][l4];
      *(float4*)Bn = *(const float4*)&sB[n][l4];
      *(float4*)Cn = *(const float4*)&sC[n][l4];

      // h-independent work (ILP across 4 steps)
      float dA[4], dBu[4];
      #pragma unroll
      for (int j = 0; j < 4; ++j) {
        float draw = dv[j] + dtb_d;
        float s = (draw > 20.f) ? draw : __logf(1.f + __expf(draw));
        dv[j]  = s;
        dA[j]  = __expf(s * An);
        dBu[j] = s * Bn[j] * xv[j];
      }
      // serial chain: 4 dependent fmas only
      float p[4];
      #pragma unroll
      for (int j = 0; j < 4; ++j) {
        h = fmaf(dA[j], h, dBu[j]);
        p[j] = h * Cn[j];
      }
      // 4 independent DPP reduction trees, level-interleaved; sum -> lane 15
      #pragma unroll
      for (int j = 0; j < 4; ++j) p[j] = dpp_shr_add<0x111>(p[j]);
      #pragma unroll
      for (int j = 0; j < 4; ++j) p[j] = dpp_shr_add<0x112>(p[j]);
      #pragma unroll
      for (int j = 0; j < 4; ++j) p[j] = dpp_shr_add<0x114>(p[j]);
      #pragma unroll
      for (int j = 0; j < 4; ++j) p[j] = dpp_shr_add<0x118>(p[j]);

      if (n == 15) {
        float o[4];
        #pragma unroll
        for (int j = 0; j < 4; ++j) {
          float y   = p[j] + xv[j] * Dd;
          float sig = 1.f / (1.f + __expf(-zv[j]));
          o[j] = y * zv[j] * sig;
        }
        *(float4*)&xrow[l0 + l4] = *(const float4*)o;
      }
    }
  }
}

// ---------------------------------------------------------------------------
extern "C" void kernel_launch(void* const* d_in, const int* in_sizes, int n_in,
                              void* d_out, int out_size, void* d_ws, size_t ws_size,
                              hipStream_t stream)
{
  const float* hs   = (const float*)d_in[0];
  const float* w1   = (const float*)d_in[1];
  const float* cw   = (const float*)d_in[2];
  const float* cb   = (const float*)d_in[3];
  const float* xpw  = (const float*)d_in[4];
  const float* dtw  = (const float*)d_in[5];
  const float* dtbp = (const float*)d_in[6];
  const float* Alog = (const float*)d_in[7];
  const float* Dw   = (const float*)d_in[8];
  const float* wo   = (const float*)d_in[9];
  float* out = (float*)d_out;

  char* ws = (char*)d_ws;
  float* xz    = (float*)ws;                                     // B*2DI*L
  float* xconv = (float*)(ws + (size_t)B_ * 2 * DI_ * L_ * 4);   // B*DI*L
  float* xdbl  = (float*)(ws + (size_t)B_ * 2 * DI_ * L_ * 4
                             + (size_t)B_ * DI_ * L_ * 4);       // B*96*L

  // K1 (bf16 MFMA): xz[b][e][l] = sum_d hs[b][l][d] * w1[e][d]
  {
    dim3 g(L_ / 128, (2 * DI_) / 128, B_);
    gemm_mfma<0, 0><<<g, 256, 0, stream>>>(w1, hs, xz,
        2 * DI_, L_, DM_, DM_, DM_, L_,
        0LL, (long long)L_ * DM_, (long long)2 * DI_ * L_);
  }

  // K2: depthwise conv + SiLU
  conv_silu_kernel<<<dim3(B_ * DI_ * L_ / 4 / 256), 256, 0, stream>>>(xz, cw, cb, xconv);

  // K3: x_dbl[b][k][l] = sum_d xpw[k][d] * xconv[b][d][l]
  {
    dim3 g(L_ / 64, 2, B_);
    gemm64<0, 1><<<g, 256, 0, stream>>>(xpw, xconv, xdbl,
        96, L_, DI_, DI_, L_, L_,
        0LL, (long long)DI_ * L_, (long long)96 * L_);
  }

  // K4: delta_raw[b][d][l] = sum_r dtw[d][r] * x_dbl[b][r][l] -> x-half of xz
  {
    dim3 g(L_ / 64, DI_ / 64, B_);
    gemm64<0, 1><<<g, 256, 0, stream>>>(dtw, xdbl, xz,
        DI_, L_, DTR_, DTR_, L_, L_,
        0LL, (long long)96 * L_, (long long)2 * DI_ * L_);
  }

  // K5: selective scan v2 (DPP reduce -> lane 15, 4-step batches)
  scan_kernel<<<dim3(B_ * DI_ / 16), 256, 0, stream>>>(xz, xconv, xdbl, Alog, dtbp, Dw);

  // K6 (bf16 MFMA, M=o): out[b][l][o] = sum_d y[b][d][l] * wo[o][d]
  {
    dim3 g(L_ / 128, DM_ / 128, B_);
    gemm_mfma<1, 1><<<g, 256, 0, stream>>>(wo, xz, out,
        DM_, L_, DI_, DI_, L_, DM_,
        0LL, (long long)2 * DI_ * L_, (long long)L_ * DM_);
  }
}

// Round 7
// 619.654 us; speedup vs baseline: 3.4163x; 1.1270x over previous
//
#include <hip/hip_runtime.h>
#include <hip/hip_bf16.h>

#define B_    2
#define L_    2048
#define DM_   1024
#define DI_   2048
#define DS_   16
#define DTR_  64

typedef __bf16 v8bf __attribute__((ext_vector_type(8)));
typedef float  v4f  __attribute__((ext_vector_type(4)));
typedef unsigned short us8 __attribute__((ext_vector_type(8)));
typedef unsigned short us4 __attribute__((ext_vector_type(4)));

__device__ __forceinline__ unsigned short f2bf(float f) {
  union { float f; unsigned u; } v; v.f = f;
  unsigned r = v.u + 0x7FFFu + ((v.u >> 16) & 1u);
  return (unsigned short)(r >> 16);
}

// DPP row_shr reduction step; after shifts 1,2,4,8 the row sum lands in lane 15.
template<int CTRL>
__device__ __forceinline__ float dpp_shr_add(float x) {
  int xi = __builtin_bit_cast(int, x);
  int yi = __builtin_amdgcn_update_dpp(xi, xi, CTRL, 0xF, 0xF, true);
  return x + __builtin_bit_cast(float, yi);
}

// ---------------------------------------------------------------------------
// bf16 MFMA GEMM, 128x128 tile, BK=32, 4 waves (2x2), 16x16x32 MFMA.
// (round-4 exact, validated)
// ---------------------------------------------------------------------------
template<int BCOL, int CT>
__global__ __launch_bounds__(256) void gemm_mfma(
    const float* __restrict__ A, const float* __restrict__ B,
    float* __restrict__ C,
    int M, int N, int K, int lda, int ldb, int ldc,
    long long sA, long long sB_, long long sC)
{
  __shared__ unsigned short lA[128 * 32];
  __shared__ unsigned short lB[128 * 32];

  const int tid  = threadIdx.x;
  const int bz   = blockIdx.z;
  A += sA  * bz;
  B += sB_ * bz;
  C += sC  * bz;

  const int m0 = blockIdx.y * 128;
  const int n0 = blockIdx.x * 128;
  const int wave = tid >> 6, lane = tid & 63;
  const int wr = wave >> 1, wc = wave & 1;
  const int lrow = lane & 15, lk = lane >> 4;

  v4f acc[4][4];
  #pragma unroll
  for (int i = 0; i < 4; ++i)
    #pragma unroll
    for (int j = 0; j < 4; ++j) acc[i][j] = (v4f)0.f;

  const int sr  = tid >> 1, skh = (tid & 1) * 16;
  const int cn4 = (tid & 31) * 4, ck4 = (tid >> 5) * 4;

  for (int k0 = 0; k0 < K; k0 += 32) {
    __syncthreads();
    {
      const float* src = A + (long long)(m0 + sr) * lda + k0 + skh;
      unsigned short tmp[16];
      #pragma unroll
      for (int q = 0; q < 4; ++q) {
        float4 v = *(const float4*)(src + q * 4);
        tmp[q*4+0] = f2bf(v.x); tmp[q*4+1] = f2bf(v.y);
        tmp[q*4+2] = f2bf(v.z); tmp[q*4+3] = f2bf(v.w);
      }
      int b0 = sr * 64 + skh * 2;
      int sw = (sr & 7) << 4;
      *(us8*)((char*)lA + ((b0)      ^ sw)) = *(us8*)tmp;
      *(us8*)((char*)lA + ((b0 + 16) ^ sw)) = *(us8*)(tmp + 8);
    }
    if (BCOL == 0) {
      const float* src = B + (long long)(n0 + sr) * ldb + k0 + skh;
      unsigned short tmp[16];
      #pragma unroll
      for (int q = 0; q < 4; ++q) {
        float4 v = *(const float4*)(src + q * 4);
        tmp[q*4+0] = f2bf(v.x); tmp[q*4+1] = f2bf(v.y);
        tmp[q*4+2] = f2bf(v.z); tmp[q*4+3] = f2bf(v.w);
      }
      int b0 = sr * 64 + skh * 2;
      int sw = (sr & 7) << 4;
      *(us8*)((char*)lB + ((b0)      ^ sw)) = *(us8*)tmp;
      *(us8*)((char*)lB + ((b0 + 16) ^ sw)) = *(us8*)(tmp + 8);
    } else {
      float va[4][4];
      #pragma unroll
      for (int kk = 0; kk < 4; ++kk) {
        float4 v = *(const float4*)(B + (long long)(k0 + ck4 + kk) * ldb + n0 + cn4);
        va[kk][0] = v.x; va[kk][1] = v.y; va[kk][2] = v.z; va[kk][3] = v.w;
      }
      #pragma unroll
      for (int nn = 0; nn < 4; ++nn) {
        us4 w;
        w[0] = f2bf(va[0][nn]); w[1] = f2bf(va[1][nn]);
        w[2] = f2bf(va[2][nn]); w[3] = f2bf(va[3][nn]);
        int row = cn4 + nn;
        int b0  = row * 64 + ck4 * 2;
        *(us4*)((char*)lB + (b0 ^ ((row & 7) << 4))) = w;
      }
    }
    __syncthreads();

    v8bf af[4], bf[4];
    #pragma unroll
    for (int i = 0; i < 4; ++i) {
      int r  = wr * 64 + i * 16 + lrow;
      int b0 = (r * 64 + lk * 16) ^ ((r & 7) << 4);
      af[i] = __builtin_bit_cast(v8bf, *(const us8*)((const char*)lA + b0));
    }
    #pragma unroll
    for (int j = 0; j < 4; ++j) {
      int r  = wc * 64 + j * 16 + lrow;
      int b0 = (r * 64 + lk * 16) ^ ((r & 7) << 4);
      bf[j] = __builtin_bit_cast(v8bf, *(const us8*)((const char*)lB + b0));
    }
    #pragma unroll
    for (int i = 0; i < 4; ++i)
      #pragma unroll
      for (int j = 0; j < 4; ++j)
        acc[i][j] = __builtin_amdgcn_mfma_f32_16x16x32_bf16(af[i], bf[j], acc[i][j], 0, 0, 0);
  }

  #pragma unroll
  for (int i = 0; i < 4; ++i) {
    #pragma unroll
    for (int j = 0; j < 4; ++j) {
      int gm = m0 + wr * 64 + i * 16 + lk * 4;
      int gn = n0 + wc * 64 + j * 16 + lrow;
      if (CT == 0) {
        #pragma unroll
        for (int r = 0; r < 4; ++r)
          C[(long long)(gm + r) * ldc + gn] = acc[i][j][r];
      } else {
        *(v4f*)&C[(long long)gn * ldc + gm] = acc[i][j];
      }
    }
  }
}

// ---------------------------------------------------------------------------
// Generic 64x64x16 fp32 tiled GEMM. ACT 1: softplus(acc + bias[m]) epilogue
// (round-2 validated epilogue path).
// ---------------------------------------------------------------------------
template<int AMODE, int BMODE, int ACT>
__global__ __launch_bounds__(256) void gemm64(
    const float* __restrict__ A, const float* __restrict__ B,
    float* __restrict__ C, const float* __restrict__ bias,
    int M, int N, int K, int lda, int ldb, int ldc,
    long long sA, long long sB_, long long sC)
{
  constexpr int BM = 64, BN = 64, BK = 16;
  __shared__ float As[BK][BM + 4];
  __shared__ float Bs[BK][BN + 4];

  const int tid = threadIdx.x;
  const int bz  = blockIdx.z;
  A += sA  * bz;
  B += sB_ * bz;
  C += sC  * bz;

  const int m0 = blockIdx.y * BM;
  const int n0 = blockIdx.x * BN;
  const int tx = tid & 15;
  const int ty = tid >> 4;

  float acc[4][4] = {};

  for (int k0 = 0; k0 < K; k0 += BK) {
    #pragma unroll
    for (int i = 0; i < 4; ++i) {
      int idx = tid + i * 256;
      int m, k;
      if (AMODE == 0) { k = idx & (BK - 1); m = idx >> 4; }
      else            { m = idx & (BM - 1); k = idx >> 6; }
      int gm = m0 + m;
      float v = 0.f;
      if (gm < M)
        v = (AMODE == 0) ? A[(long long)gm * lda + (k0 + k)]
                         : A[(long long)(k0 + k) * lda + gm];
      As[k][m] = v;
    }
    #pragma unroll
    for (int i = 0; i < 4; ++i) {
      int idx = tid + i * 256;
      int n, k;
      if (BMODE == 0) { k = idx & (BK - 1); n = idx >> 4; }
      else            { n = idx & (BN - 1); k = idx >> 6; }
      int gn = n0 + n;
      float v = (BMODE == 0) ? B[(long long)gn * ldb + (k0 + k)]
                             : B[(long long)(k0 + k) * ldb + gn];
      Bs[k][n] = v;
    }
    __syncthreads();

    #pragma unroll
    for (int k = 0; k < BK; ++k) {
      float4 av = *(const float4*)&As[k][ty * 4];
      float4 bv = *(const float4*)&Bs[k][tx * 4];
      float a_[4] = {av.x, av.y, av.z, av.w};
      float b_[4] = {bv.x, bv.y, bv.z, bv.w};
      #pragma unroll
      for (int i = 0; i < 4; ++i)
        #pragma unroll
        for (int j = 0; j < 4; ++j)
          acc[i][j] = fmaf(a_[i], b_[j], acc[i][j]);
    }
    __syncthreads();
  }

  #pragma unroll
  for (int i = 0; i < 4; ++i) {
    int gm = m0 + ty * 4 + i;
    if (gm < M) {
      float bv = (ACT == 1) ? bias[gm] : 0.f;
      #pragma unroll
      for (int j = 0; j < 4; ++j) {
        float v = acc[i][j];
        if (ACT == 1) {
          v += bv;
          v = (v > 20.f) ? v : log1pf(__expf(v));
        }
        C[(long long)gm * ldc + n0 + tx * 4 + j] = v;
      }
    }
  }
}

// ---------------------------------------------------------------------------
// Depthwise causal conv (k=4) + bias + SiLU (round-1 exact).
// ---------------------------------------------------------------------------
__global__ __launch_bounds__(256) void conv_silu_kernel(
    const float* __restrict__ xz, const float* __restrict__ cw,
    const float* __restrict__ cb, float* __restrict__ xc)
{
  int idx = blockIdx.x * 256 + threadIdx.x;
  int l4  = (idx & (L_ / 4 - 1)) << 2;
  int row = idx >> 9;
  int d   = row & (DI_ - 1);
  int b   = row >> 11;

  const float* in = xz + ((size_t)b * 2 * DI_ + d) * L_;
  float w0 = cw[d * 4 + 0], w1 = cw[d * 4 + 1];
  float w2 = cw[d * 4 + 2], w3 = cw[d * 4 + 3];
  float bias = cb[d];

  float o[4];
  #pragma unroll
  for (int j = 0; j < 4; ++j) {
    int l = l4 + j;
    float acc = bias + in[l] * w3;
    if (l >= 1) acc += in[l - 1] * w2;
    if (l >= 2) acc += in[l - 2] * w1;
    if (l >= 3) acc += in[l - 3] * w0;
    float sig = 1.f / (1.f + __expf(-acc));
    o[j] = acc * sig;
  }
  *(float4*)&xc[(size_t)row * L_ + l4] = *(float4*)o;
}

// ---------------------------------------------------------------------------
// Selective scan v3: round-6 skeleton, but dv is ALREADY softplus'd (K4
// epilogue), 8-step batches, async-staged global prefetch (T14), z read
// only by the emitting lane.
// ---------------------------------------------------------------------------
__global__ __launch_bounds__(256) void scan_kernel(
    float* __restrict__ xz, const float* __restrict__ xconv,
    const float* __restrict__ x_dbl, const float* __restrict__ A_log,
    const float* __restrict__ Dw)
{
  const int tid = threadIdx.x;
  const int g   = tid >> 4;          // channel group within block
  const int n   = tid & 15;          // state lane
  const int gid = blockIdx.x * 16 + g;
  const int b   = gid >> 11;
  const int d   = gid & (DI_ - 1);
  const int bb  = blockIdx.x >> 7;
  const int d0  = (blockIdx.x << 4) & (DI_ - 1);

  const float An = -expf(A_log[d * DS_ + n]);
  const float Dd = Dw[d];

  float*       xrow  = xz + ((size_t)b * 2 * DI_ + d) * L_;          // y out
  const float* Bbase = x_dbl + ((size_t)b * 96 + DTR_) * L_;
  const float* Cbase = x_dbl + ((size_t)b * 96 + DTR_ + DS_) * L_;

  const float* drow0 = xz    + ((size_t)bb * 2 * DI_ + d0) * L_;
  const float* zrow0 = xz    + ((size_t)bb * 2 * DI_ + DI_ + d0) * L_;
  const float* xrow0 = xconv + ((size_t)bb * DI_ + d0) * L_;

  __shared__ float sD[16][68], sX[16][68], sZ[16][68];
  __shared__ float sB[16][68], sC[16][68];

  const int sr = tid >> 4, sc4 = (tid & 15) * 4;
  const size_t soff = (size_t)sr * L_ + sc4;

  // T14 prefetch: chunk 0 into registers
  float4 rD = *(const float4*)&drow0[soff];
  float4 rX = *(const float4*)&xrow0[soff];
  float4 rZ = *(const float4*)&zrow0[soff];
  float4 rB = *(const float4*)&Bbase[soff];
  float4 rC = *(const float4*)&Cbase[soff];

  float h = 0.f;
  for (int l0 = 0; l0 < L_; l0 += 64) {
    __syncthreads();                    // previous chunk's compute done
    *(float4*)&sD[sr][sc4] = rD;
    *(float4*)&sX[sr][sc4] = rX;
    *(float4*)&sZ[sr][sc4] = rZ;
    *(float4*)&sB[sr][sc4] = rB;
    *(float4*)&sC[sr][sc4] = rC;
    __syncthreads();

    // issue next chunk's loads; consumed after next barrier (latency hidden
    // under the 8 batches of compute below)
    if (l0 + 64 < L_) {
      rD = *(const float4*)&drow0[soff + l0 + 64];
      rX = *(const float4*)&xrow0[soff + l0 + 64];
      rZ = *(const float4*)&zrow0[soff + l0 + 64];
      rB = *(const float4*)&Bbase[soff + l0 + 64];
      rC = *(const float4*)&Cbase[soff + l0 + 64];
    }

    #pragma unroll
    for (int l8 = 0; l8 < 64; l8 += 8) {
      float dv[8], xv[8], Bn[8], Cn[8];
      *(float4*)&dv[0] = *(const float4*)&sD[g][l8];
      *(float4*)&dv[4] = *(const float4*)&sD[g][l8 + 4];
      *(float4*)&xv[0] = *(const float4*)&sX[g][l8];
      *(float4*)&xv[4] = *(const float4*)&sX[g][l8 + 4];
      *(float4*)&Bn[0] = *(const float4*)&sB[n][l8];
      *(float4*)&Bn[4] = *(const float4*)&sB[n][l8 + 4];
      *(float4*)&Cn[0] = *(const float4*)&sC[n][l8];
      *(float4*)&Cn[4] = *(const float4*)&sC[n][l8 + 4];

      // h-independent work (dv already softplus'd by K4)
      float dA[8], dBu[8];
      #pragma unroll
      for (int j = 0; j < 8; ++j) {
        dA[j]  = __expf(dv[j] * An);
        dBu[j] = dv[j] * Bn[j] * xv[j];
      }
      // serial chain: 8 dependent fmas
      float p[8];
      #pragma unroll
      for (int j = 0; j < 8; ++j) {
        h = fmaf(dA[j], h, dBu[j]);
        p[j] = h * Cn[j];
      }
      // 8 interleaved DPP reduction trees; sum lands in lane n=15
      #pragma unroll
      for (int j = 0; j < 8; ++j) p[j] = dpp_shr_add<0x111>(p[j]);
      #pragma unroll
      for (int j = 0; j < 8; ++j) p[j] = dpp_shr_add<0x112>(p[j]);
      #pragma unroll
      for (int j = 0; j < 8; ++j) p[j] = dpp_shr_add<0x114>(p[j]);
      #pragma unroll
      for (int j = 0; j < 8; ++j) p[j] = dpp_shr_add<0x118>(p[j]);

      if (n == 15) {
        float zv[8], o[8];
        *(float4*)&zv[0] = *(const float4*)&sZ[g][l8];
        *(float4*)&zv[4] = *(const float4*)&sZ[g][l8 + 4];
        #pragma unroll
        for (int j = 0; j < 8; ++j) {
          float y   = p[j] + xv[j] * Dd;
          float sig = 1.f / (1.f + __expf(-zv[j]));
          o[j] = y * zv[j] * sig;
        }
        *(float4*)&xrow[l0 + l8]     = *(const float4*)&o[0];
        *(float4*)&xrow[l0 + l8 + 4] = *(const float4*)&o[4];
      }
    }
  }
}

// ---------------------------------------------------------------------------
extern "C" void kernel_launch(void* const* d_in, const int* in_sizes, int n_in,
                              void* d_out, int out_size, void* d_ws, size_t ws_size,
                              hipStream_t stream)
{
  const float* hs   = (const float*)d_in[0];
  const float* w1   = (const float*)d_in[1];
  const float* cw   = (const float*)d_in[2];
  const float* cb   = (const float*)d_in[3];
  const float* xpw  = (const float*)d_in[4];
  const float* dtw  = (const float*)d_in[5];
  const float* dtbp = (const float*)d_in[6];
  const float* Alog = (const float*)d_in[7];
  const float* Dw   = (const float*)d_in[8];
  const float* wo   = (const float*)d_in[9];
  float* out = (float*)d_out;

  char* ws = (char*)d_ws;
  float* xz    = (float*)ws;                                     // B*2DI*L
  float* xconv = (float*)(ws + (size_t)B_ * 2 * DI_ * L_ * 4);   // B*DI*L
  float* xdbl  = (float*)(ws + (size_t)B_ * 2 * DI_ * L_ * 4
                             + (size_t)B_ * DI_ * L_ * 4);       // B*96*L

  // K1 (bf16 MFMA): xz[b][e][l] = sum_d hs[b][l][d] * w1[e][d]
  {
    dim3 g(L_ / 128, (2 * DI_) / 128, B_);
    gemm_mfma<0, 0><<<g, 256, 0, stream>>>(w1, hs, xz,
        2 * DI_, L_, DM_, DM_, DM_, L_,
        0LL, (long long)L_ * DM_, (long long)2 * DI_ * L_);
  }

  // K2: depthwise conv + SiLU
  conv_silu_kernel<<<dim3(B_ * DI_ * L_ / 4 / 256), 256, 0, stream>>>(xz, cw, cb, xconv);

  // K3: x_dbl[b][k][l] = sum_d xpw[k][d] * xconv[b][d][l]
  {
    dim3 g(L_ / 64, 2, B_);
    gemm64<0, 1, 0><<<g, 256, 0, stream>>>(xpw, xconv, xdbl, nullptr,
        96, L_, DI_, DI_, L_, L_,
        0LL, (long long)DI_ * L_, (long long)96 * L_);
  }

  // K4: dv[b][d][l] = softplus(sum_r dtw[d][r]*x_dbl[b][r][l] + dtb[d])
  {
    dim3 g(L_ / 64, DI_ / 64, B_);
    gemm64<0, 1, 1><<<g, 256, 0, stream>>>(dtw, xdbl, xz, dtbp,
        DI_, L_, DTR_, DTR_, L_, L_,
        0LL, (long long)96 * L_, (long long)2 * DI_ * L_);
  }

  // K5: selective scan v3 (softplus pre-applied, 8-step batches, T14 prefetch)
  scan_kernel<<<dim3(B_ * DI_ / 16), 256, 0, stream>>>(xz, xconv, xdbl, Alog, Dw);

  // K6 (bf16 MFMA, M=o): out[b][l][o] = sum_d y[b][d][l] * wo[o][d]
  {
    dim3 g(L_ / 128, DM_ / 128, B_);
    gemm_mfma<1, 1><<<g, 256, 0, stream>>>(wo, xz, out,
        DM_, L_, DI_, DI_, L_, DM_,
        0LL, (long long)2 * DI_ * L_, (long long)L_ * DM_);
  }
}

// Round 8
// 483.416 us; speedup vs baseline: 4.3791x; 1.2818x over previous
//
#include <hip/hip_runtime.h>
#include <hip/hip_bf16.h>

#define B_    2
#define L_    2048
#define DM_   1024
#define DI_   2048
#define DS_   16
#define DTR_  64

typedef __bf16 v8bf __attribute__((ext_vector_type(8)));
typedef float  v4f  __attribute__((ext_vector_type(4)));
typedef unsigned short us8 __attribute__((ext_vector_type(8)));
typedef unsigned short us4 __attribute__((ext_vector_type(4)));

__device__ __forceinline__ unsigned short f2bf(float f) {
  union { float f; unsigned u; } v; v.f = f;
  unsigned r = v.u + 0x7FFFu + ((v.u >> 16) & 1u);
  return (unsigned short)(r >> 16);
}

// DPP row_shr reduction step; after shifts 1,2,4,8 the row sum lands in lane 15.
template<int CTRL>
__device__ __forceinline__ float dpp_shr_add(float x) {
  int xi = __builtin_bit_cast(int, x);
  int yi = __builtin_amdgcn_update_dpp(xi, xi, CTRL, 0xF, 0xF, true);
  return x + __builtin_bit_cast(float, yi);
}

// ---------------------------------------------------------------------------
// bf16 MFMA GEMM, 128x128 tile, BK=32, 4 waves (2x2), 16x16x32 MFMA.
// (round-4 exact, validated)
// ---------------------------------------------------------------------------
template<int BCOL, int CT>
__global__ __launch_bounds__(256) void gemm_mfma(
    const float* __restrict__ A, const float* __restrict__ B,
    float* __restrict__ C,
    int M, int N, int K, int lda, int ldb, int ldc,
    long long sA, long long sB_, long long sC)
{
  __shared__ unsigned short lA[128 * 32];
  __shared__ unsigned short lB[128 * 32];

  const int tid  = threadIdx.x;
  const int bz   = blockIdx.z;
  A += sA  * bz;
  B += sB_ * bz;
  C += sC  * bz;

  const int m0 = blockIdx.y * 128;
  const int n0 = blockIdx.x * 128;
  const int wave = tid >> 6, lane = tid & 63;
  const int wr = wave >> 1, wc = wave & 1;
  const int lrow = lane & 15, lk = lane >> 4;

  v4f acc[4][4];
  #pragma unroll
  for (int i = 0; i < 4; ++i)
    #pragma unroll
    for (int j = 0; j < 4; ++j) acc[i][j] = (v4f)0.f;

  const int sr  = tid >> 1, skh = (tid & 1) * 16;
  const int cn4 = (tid & 31) * 4, ck4 = (tid >> 5) * 4;

  for (int k0 = 0; k0 < K; k0 += 32) {
    __syncthreads();
    {
      const float* src = A + (long long)(m0 + sr) * lda + k0 + skh;
      unsigned short tmp[16];
      #pragma unroll
      for (int q = 0; q < 4; ++q) {
        float4 v = *(const float4*)(src + q * 4);
        tmp[q*4+0] = f2bf(v.x); tmp[q*4+1] = f2bf(v.y);
        tmp[q*4+2] = f2bf(v.z); tmp[q*4+3] = f2bf(v.w);
      }
      int b0 = sr * 64 + skh * 2;
      int sw = (sr & 7) << 4;
      *(us8*)((char*)lA + ((b0)      ^ sw)) = *(us8*)tmp;
      *(us8*)((char*)lA + ((b0 + 16) ^ sw)) = *(us8*)(tmp + 8);
    }
    if (BCOL == 0) {
      const float* src = B + (long long)(n0 + sr) * ldb + k0 + skh;
      unsigned short tmp[16];
      #pragma unroll
      for (int q = 0; q < 4; ++q) {
        float4 v = *(const float4*)(src + q * 4);
        tmp[q*4+0] = f2bf(v.x); tmp[q*4+1] = f2bf(v.y);
        tmp[q*4+2] = f2bf(v.z); tmp[q*4+3] = f2bf(v.w);
      }
      int b0 = sr * 64 + skh * 2;
      int sw = (sr & 7) << 4;
      *(us8*)((char*)lB + ((b0)      ^ sw)) = *(us8*)tmp;
      *(us8*)((char*)lB + ((b0 + 16) ^ sw)) = *(us8*)(tmp + 8);
    } else {
      float va[4][4];
      #pragma unroll
      for (int kk = 0; kk < 4; ++kk) {
        float4 v = *(const float4*)(B + (long long)(k0 + ck4 + kk) * ldb + n0 + cn4);
        va[kk][0] = v.x; va[kk][1] = v.y; va[kk][2] = v.z; va[kk][3] = v.w;
      }
      #pragma unroll
      for (int nn = 0; nn < 4; ++nn) {
        us4 w;
        w[0] = f2bf(va[0][nn]); w[1] = f2bf(va[1][nn]);
        w[2] = f2bf(va[2][nn]); w[3] = f2bf(va[3][nn]);
        int row = cn4 + nn;
        int b0  = row * 64 + ck4 * 2;
        *(us4*)((char*)lB + (b0 ^ ((row & 7) << 4))) = w;
      }
    }
    __syncthreads();

    v8bf af[4], bf[4];
    #pragma unroll
    for (int i = 0; i < 4; ++i) {
      int r  = wr * 64 + i * 16 + lrow;
      int b0 = (r * 64 + lk * 16) ^ ((r & 7) << 4);
      af[i] = __builtin_bit_cast(v8bf, *(const us8*)((const char*)lA + b0));
    }
    #pragma unroll
    for (int j = 0; j < 4; ++j) {
      int r  = wc * 64 + j * 16 + lrow;
      int b0 = (r * 64 + lk * 16) ^ ((r & 7) << 4);
      bf[j] = __builtin_bit_cast(v8bf, *(const us8*)((const char*)lB + b0));
    }
    #pragma unroll
    for (int i = 0; i < 4; ++i)
      #pragma unroll
      for (int j = 0; j < 4; ++j)
        acc[i][j] = __builtin_amdgcn_mfma_f32_16x16x32_bf16(af[i], bf[j], acc[i][j], 0, 0, 0);
  }

  #pragma unroll
  for (int i = 0; i < 4; ++i) {
    #pragma unroll
    for (int j = 0; j < 4; ++j) {
      int gm = m0 + wr * 64 + i * 16 + lk * 4;
      int gn = n0 + wc * 64 + j * 16 + lrow;
      if (CT == 0) {
        #pragma unroll
        for (int r = 0; r < 4; ++r)
          C[(long long)(gm + r) * ldc + gn] = acc[i][j][r];
      } else {
        *(v4f*)&C[(long long)gn * ldc + gm] = acc[i][j];
      }
    }
  }
}

// ---------------------------------------------------------------------------
// Generic 64x64x16 fp32 tiled GEMM. ACT 1: softplus(acc + bias[m]) epilogue.
// ---------------------------------------------------------------------------
template<int AMODE, int BMODE, int ACT>
__global__ __launch_bounds__(256) void gemm64(
    const float* __restrict__ A, const float* __restrict__ B,
    float* __restrict__ C, const float* __restrict__ bias,
    int M, int N, int K, int lda, int ldb, int ldc,
    long long sA, long long sB_, long long sC)
{
  constexpr int BM = 64, BN = 64, BK = 16;
  __shared__ float As[BK][BM + 4];
  __shared__ float Bs[BK][BN + 4];

  const int tid = threadIdx.x;
  const int bz  = blockIdx.z;
  A += sA  * bz;
  B += sB_ * bz;
  C += sC  * bz;

  const int m0 = blockIdx.y * BM;
  const int n0 = blockIdx.x * BN;
  const int tx = tid & 15;
  const int ty = tid >> 4;

  float acc[4][4] = {};

  for (int k0 = 0; k0 < K; k0 += BK) {
    #pragma unroll
    for (int i = 0; i < 4; ++i) {
      int idx = tid + i * 256;
      int m, k;
      if (AMODE == 0) { k = idx & (BK - 1); m = idx >> 4; }
      else            { m = idx & (BM - 1); k = idx >> 6; }
      int gm = m0 + m;
      float v = 0.f;
      if (gm < M)
        v = (AMODE == 0) ? A[(long long)gm * lda + (k0 + k)]
                         : A[(long long)(k0 + k) * lda + gm];
      As[k][m] = v;
    }
    #pragma unroll
    for (int i = 0; i < 4; ++i) {
      int idx = tid + i * 256;
      int n, k;
      if (BMODE == 0) { k = idx & (BK - 1); n = idx >> 4; }
      else            { n = idx & (BN - 1); k = idx >> 6; }
      int gn = n0 + n;
      float v = (BMODE == 0) ? B[(long long)gn * ldb + (k0 + k)]
                             : B[(long long)(k0 + k) * ldb + gn];
      Bs[k][n] = v;
    }
    __syncthreads();

    #pragma unroll
    for (int k = 0; k < BK; ++k) {
      float4 av = *(const float4*)&As[k][ty * 4];
      float4 bv = *(const float4*)&Bs[k][tx * 4];
      float a_[4] = {av.x, av.y, av.z, av.w};
      float b_[4] = {bv.x, bv.y, bv.z, bv.w};
      #pragma unroll
      for (int i = 0; i < 4; ++i)
        #pragma unroll
        for (int j = 0; j < 4; ++j)
          acc[i][j] = fmaf(a_[i], b_[j], acc[i][j]);
    }
    __syncthreads();
  }

  #pragma unroll
  for (int i = 0; i < 4; ++i) {
    int gm = m0 + ty * 4 + i;
    if (gm < M) {
      float bv = (ACT == 1) ? bias[gm] : 0.f;
      #pragma unroll
      for (int j = 0; j < 4; ++j) {
        float v = acc[i][j];
        if (ACT == 1) {
          v += bv;
          v = (v > 20.f) ? v : log1pf(__expf(v));
        }
        C[(long long)gm * ldc + n0 + tx * 4 + j] = v;
      }
    }
  }
}

// ---------------------------------------------------------------------------
// Split-K GEMM for K3 (M=96, K=2048 -> 8 chunks of 256). AMODE0/BMODE1 fixed.
// grid (N/64, 2*KC, B); blockIdx.y = mblk + 2*kc. atomicAdd into C.
// ---------------------------------------------------------------------------
#define KC_   8
__global__ __launch_bounds__(256) void gemm64_sk(
    const float* __restrict__ A, const float* __restrict__ B,
    float* __restrict__ C,
    int M, int N, int K, int lda, int ldb, int ldc,
    long long sB_, long long sC)
{
  constexpr int BM = 64, BN = 64, BK = 16;
  __shared__ float As[BK][BM + 4];
  __shared__ float Bs[BK][BN + 4];

  const int tid = threadIdx.x;
  const int bz  = blockIdx.z;
  B += sB_ * bz;
  C += sC  * bz;

  const int m0  = (blockIdx.y & 1) * BM;
  const int kc  = blockIdx.y >> 1;
  const int n0  = blockIdx.x * BN;
  const int kend = (kc + 1) * (K / KC_);
  const int tx = tid & 15;
  const int ty = tid >> 4;

  float acc[4][4] = {};

  for (int k0 = kc * (K / KC_); k0 < kend; k0 += BK) {
    #pragma unroll
    for (int i = 0; i < 4; ++i) {
      int idx = tid + i * 256;
      int k = idx & (BK - 1), m = idx >> 4;
      int gm = m0 + m;
      As[k][m] = (gm < M) ? A[(long long)gm * lda + (k0 + k)] : 0.f;
    }
    #pragma unroll
    for (int i = 0; i < 4; ++i) {
      int idx = tid + i * 256;
      int n = idx & (BN - 1), k = idx >> 6;
      Bs[k][n] = B[(long long)(k0 + k) * ldb + (n0 + n)];
    }
    __syncthreads();

    #pragma unroll
    for (int k = 0; k < BK; ++k) {
      float4 av = *(const float4*)&As[k][ty * 4];
      float4 bv = *(const float4*)&Bs[k][tx * 4];
      float a_[4] = {av.x, av.y, av.z, av.w};
      float b_[4] = {bv.x, bv.y, bv.z, bv.w};
      #pragma unroll
      for (int i = 0; i < 4; ++i)
        #pragma unroll
        for (int j = 0; j < 4; ++j)
          acc[i][j] = fmaf(a_[i], b_[j], acc[i][j]);
    }
    __syncthreads();
  }

  #pragma unroll
  for (int i = 0; i < 4; ++i) {
    int gm = m0 + ty * 4 + i;
    if (gm < M) {
      #pragma unroll
      for (int j = 0; j < 4; ++j)
        atomicAdd(&C[(long long)gm * ldc + n0 + tx * 4 + j], acc[i][j]);
    }
  }
}

// zero-fill (float4 per thread)
__global__ __launch_bounds__(256) void zero_kernel(float* __restrict__ p) {
  int i = blockIdx.x * 256 + threadIdx.x;
  *(float4*)&p[(size_t)i * 4] = make_float4(0.f, 0.f, 0.f, 0.f);
}

// ---------------------------------------------------------------------------
// Depthwise causal conv (k=4) + bias + SiLU (round-1 exact).
// ---------------------------------------------------------------------------
__global__ __launch_bounds__(256) void conv_silu_kernel(
    const float* __restrict__ xz, const float* __restrict__ cw,
    const float* __restrict__ cb, float* __restrict__ xc)
{
  int idx = blockIdx.x * 256 + threadIdx.x;
  int l4  = (idx & (L_ / 4 - 1)) << 2;
  int row = idx >> 9;
  int d   = row & (DI_ - 1);
  int b   = row >> 11;

  const float* in = xz + ((size_t)b * 2 * DI_ + d) * L_;
  float w0 = cw[d * 4 + 0], w1 = cw[d * 4 + 1];
  float w2 = cw[d * 4 + 2], w3 = cw[d * 4 + 3];
  float bias = cb[d];

  float o[4];
  #pragma unroll
  for (int j = 0; j < 4; ++j) {
    int l = l4 + j;
    float acc = bias + in[l] * w3;
    if (l >= 1) acc += in[l - 1] * w2;
    if (l >= 2) acc += in[l - 2] * w1;
    if (l >= 3) acc += in[l - 3] * w0;
    float sig = 1.f / (1.f + __expf(-acc));
    o[j] = acc * sig;
  }
  *(float4*)&xc[(size_t)row * L_ + l4] = *(float4*)o;
}

// ---------------------------------------------------------------------------
// Selective scan v3 (round-7 exact): dv pre-softplus'd, 8-step batches,
// T14 register prefetch, DPP reduce -> lane 15.
// ---------------------------------------------------------------------------
__global__ __launch_bounds__(256) void scan_kernel(
    float* __restrict__ xz, const float* __restrict__ xconv,
    const float* __restrict__ x_dbl, const float* __restrict__ A_log,
    const float* __restrict__ Dw)
{
  const int tid = threadIdx.x;
  const int g   = tid >> 4;
  const int n   = tid & 15;
  const int gid = blockIdx.x * 16 + g;
  const int b   = gid >> 11;
  const int d   = gid & (DI_ - 1);
  const int bb  = blockIdx.x >> 7;
  const int d0  = (blockIdx.x << 4) & (DI_ - 1);

  const float An = -expf(A_log[d * DS_ + n]);
  const float Dd = Dw[d];

  float*       xrow  = xz + ((size_t)b * 2 * DI_ + d) * L_;
  const float* Bbase = x_dbl + ((size_t)b * 96 + DTR_) * L_;
  const float* Cbase = x_dbl + ((size_t)b * 96 + DTR_ + DS_) * L_;

  const float* drow0 = xz    + ((size_t)bb * 2 * DI_ + d0) * L_;
  const float* zrow0 = xz    + ((size_t)bb * 2 * DI_ + DI_ + d0) * L_;
  const float* xrow0 = xconv + ((size_t)bb * DI_ + d0) * L_;

  __shared__ float sD[16][68], sX[16][68], sZ[16][68];
  __shared__ float sB[16][68], sC[16][68];

  const int sr = tid >> 4, sc4 = (tid & 15) * 4;
  const size_t soff = (size_t)sr * L_ + sc4;

  float4 rD = *(const float4*)&drow0[soff];
  float4 rX = *(const float4*)&xrow0[soff];
  float4 rZ = *(const float4*)&zrow0[soff];
  float4 rB = *(const float4*)&Bbase[soff];
  float4 rC = *(const float4*)&Cbase[soff];

  float h = 0.f;
  for (int l0 = 0; l0 < L_; l0 += 64) {
    __syncthreads();
    *(float4*)&sD[sr][sc4] = rD;
    *(float4*)&sX[sr][sc4] = rX;
    *(float4*)&sZ[sr][sc4] = rZ;
    *(float4*)&sB[sr][sc4] = rB;
    *(float4*)&sC[sr][sc4] = rC;
    __syncthreads();

    if (l0 + 64 < L_) {
      rD = *(const float4*)&drow0[soff + l0 + 64];
      rX = *(const float4*)&xrow0[soff + l0 + 64];
      rZ = *(const float4*)&zrow0[soff + l0 + 64];
      rB = *(const float4*)&Bbase[soff + l0 + 64];
      rC = *(const float4*)&Cbase[soff + l0 + 64];
    }

    #pragma unroll
    for (int l8 = 0; l8 < 64; l8 += 8) {
      float dv[8], xv[8], Bn[8], Cn[8];
      *(float4*)&dv[0] = *(const float4*)&sD[g][l8];
      *(float4*)&dv[4] = *(const float4*)&sD[g][l8 + 4];
      *(float4*)&xv[0] = *(const float4*)&sX[g][l8];
      *(float4*)&xv[4] = *(const float4*)&sX[g][l8 + 4];
      *(float4*)&Bn[0] = *(const float4*)&sB[n][l8];
      *(float4*)&Bn[4] = *(const float4*)&sB[n][l8 + 4];
      *(float4*)&Cn[0] = *(const float4*)&sC[n][l8];
      *(float4*)&Cn[4] = *(const float4*)&sC[n][l8 + 4];

      float dA[8], dBu[8];
      #pragma unroll
      for (int j = 0; j < 8; ++j) {
        dA[j]  = __expf(dv[j] * An);
        dBu[j] = dv[j] * Bn[j] * xv[j];
      }
      float p[8];
      #pragma unroll
      for (int j = 0; j < 8; ++j) {
        h = fmaf(dA[j], h, dBu[j]);
        p[j] = h * Cn[j];
      }
      #pragma unroll
      for (int j = 0; j < 8; ++j) p[j] = dpp_shr_add<0x111>(p[j]);
      #pragma unroll
      for (int j = 0; j < 8; ++j) p[j] = dpp_shr_add<0x112>(p[j]);
      #pragma unroll
      for (int j = 0; j < 8; ++j) p[j] = dpp_shr_add<0x114>(p[j]);
      #pragma unroll
      for (int j = 0; j < 8; ++j) p[j] = dpp_shr_add<0x118>(p[j]);

      if (n == 15) {
        float zv[8], o[8];
        *(float4*)&zv[0] = *(const float4*)&sZ[g][l8];
        *(float4*)&zv[4] = *(const float4*)&sZ[g][l8 + 4];
        #pragma unroll
        for (int j = 0; j < 8; ++j) {
          float y   = p[j] + xv[j] * Dd;
          float sig = 1.f / (1.f + __expf(-zv[j]));
          o[j] = y * zv[j] * sig;
        }
        *(float4*)&xrow[l0 + l8]     = *(const float4*)&o[0];
        *(float4*)&xrow[l0 + l8 + 4] = *(const float4*)&o[4];
      }
    }
  }
}

// ---------------------------------------------------------------------------
extern "C" void kernel_launch(void* const* d_in, const int* in_sizes, int n_in,
                              void* d_out, int out_size, void* d_ws, size_t ws_size,
                              hipStream_t stream)
{
  const float* hs   = (const float*)d_in[0];
  const float* w1   = (const float*)d_in[1];
  const float* cw   = (const float*)d_in[2];
  const float* cb   = (const float*)d_in[3];
  const float* xpw  = (const float*)d_in[4];
  const float* dtw  = (const float*)d_in[5];
  const float* dtbp = (const float*)d_in[6];
  const float* Alog = (const float*)d_in[7];
  const float* Dw   = (const float*)d_in[8];
  const float* wo   = (const float*)d_in[9];
  float* out = (float*)d_out;

  char* ws = (char*)d_ws;
  float* xz    = (float*)ws;                                     // B*2DI*L
  float* xconv = (float*)(ws + (size_t)B_ * 2 * DI_ * L_ * 4);   // B*DI*L
  float* xdbl  = (float*)(ws + (size_t)B_ * 2 * DI_ * L_ * 4
                             + (size_t)B_ * DI_ * L_ * 4);       // B*96*L

  // K1 (bf16 MFMA): xz[b][e][l] = sum_d hs[b][l][d] * w1[e][d]
  {
    dim3 g(L_ / 128, (2 * DI_) / 128, B_);
    gemm_mfma<0, 0><<<g, 256, 0, stream>>>(w1, hs, xz,
        2 * DI_, L_, DM_, DM_, DM_, L_,
        0LL, (long long)L_ * DM_, (long long)2 * DI_ * L_);
  }

  // K2: depthwise conv + SiLU
  conv_silu_kernel<<<dim3(B_ * DI_ * L_ / 4 / 256), 256, 0, stream>>>(xz, cw, cb, xconv);

  // K3 (split-K + atomics): x_dbl[b][k][l] = sum_d xpw[k][d] * xconv[b][d][l]
  zero_kernel<<<dim3(B_ * 96 * L_ / 4 / 256), 256, 0, stream>>>(xdbl);
  {
    dim3 g(L_ / 64, 2 * KC_, B_);
    gemm64_sk<<<g, 256, 0, stream>>>(xpw, xconv, xdbl,
        96, L_, DI_, DI_, L_, L_,
        (long long)DI_ * L_, (long long)96 * L_);
  }

  // K4: dv[b][d][l] = softplus(sum_r dtw[d][r]*x_dbl[b][r][l] + dtb[d])
  {
    dim3 g(L_ / 64, DI_ / 64, B_);
    gemm64<0, 1, 1><<<g, 256, 0, stream>>>(dtw, xdbl, xz, dtbp,
        DI_, L_, DTR_, DTR_, L_, L_,
        0LL, (long long)96 * L_, (long long)2 * DI_ * L_);
  }

  // K5: selective scan v3
  scan_kernel<<<dim3(B_ * DI_ / 16), 256, 0, stream>>>(xz, xconv, xdbl, Alog, Dw);

  // K6 (bf16 MFMA, M=o): out[b][l][o] = sum_d y[b][d][l] * wo[o][d]
  {
    dim3 g(L_ / 128, DM_ / 128, B_);
    gemm_mfma<1, 1><<<g, 256, 0, stream>>>(wo, xz, out,
        DM_, L_, DI_, DI_, L_, DM_,
        0LL, (long long)2 * DI_ * L_, (long long)L_ * DM_);
  }
}

// Round 9
// 450.440 us; speedup vs baseline: 4.6997x; 1.0732x over previous
//
#include <hip/hip_runtime.h>
#include <hip/hip_bf16.h>

#define B_    2
#define L_    2048
#define DM_   1024
#define DI_   2048
#define DS_   16
#define DTR_  64
#define KC_   8

typedef __bf16 v8bf __attribute__((ext_vector_type(8)));
typedef float  v4f  __attribute__((ext_vector_type(4)));
typedef unsigned short us8 __attribute__((ext_vector_type(8)));
typedef unsigned short us4 __attribute__((ext_vector_type(4)));

__device__ __forceinline__ unsigned short f2bf(float f) {
  union { float f; unsigned u; } v; v.f = f;
  unsigned r = v.u + 0x7FFFu + ((v.u >> 16) & 1u);
  return (unsigned short)(r >> 16);
}

// DPP row_shr reduction step; after shifts 1,2,4,8 the row sum lands in lane 15.
template<int CTRL>
__device__ __forceinline__ float dpp_shr_add(float x) {
  int xi = __builtin_bit_cast(int, x);
  int yi = __builtin_amdgcn_update_dpp(xi, xi, CTRL, 0xF, 0xF, true);
  return x + __builtin_bit_cast(float, yi);
}

// ---------------------------------------------------------------------------
// bf16 MFMA GEMM, 128x128 tile, BK=32, 4 waves (2x2), 16x16x32 MFMA.
// (round-4 exact, validated)
// ---------------------------------------------------------------------------
template<int BCOL, int CT>
__global__ __launch_bounds__(256) void gemm_mfma(
    const float* __restrict__ A, const float* __restrict__ B,
    float* __restrict__ C,
    int M, int N, int K, int lda, int ldb, int ldc,
    long long sA, long long sB_, long long sC)
{
  __shared__ unsigned short lA[128 * 32];
  __shared__ unsigned short lB[128 * 32];

  const int tid  = threadIdx.x;
  const int bz   = blockIdx.z;
  A += sA  * bz;
  B += sB_ * bz;
  C += sC  * bz;

  const int m0 = blockIdx.y * 128;
  const int n0 = blockIdx.x * 128;
  const int wave = tid >> 6, lane = tid & 63;
  const int wr = wave >> 1, wc = wave & 1;
  const int lrow = lane & 15, lk = lane >> 4;

  v4f acc[4][4];
  #pragma unroll
  for (int i = 0; i < 4; ++i)
    #pragma unroll
    for (int j = 0; j < 4; ++j) acc[i][j] = (v4f)0.f;

  const int sr  = tid >> 1, skh = (tid & 1) * 16;
  const int cn4 = (tid & 31) * 4, ck4 = (tid >> 5) * 4;

  for (int k0 = 0; k0 < K; k0 += 32) {
    __syncthreads();
    {
      const float* src = A + (long long)(m0 + sr) * lda + k0 + skh;
      unsigned short tmp[16];
      #pragma unroll
      for (int q = 0; q < 4; ++q) {
        float4 v = *(const float4*)(src + q * 4);
        tmp[q*4+0] = f2bf(v.x); tmp[q*4+1] = f2bf(v.y);
        tmp[q*4+2] = f2bf(v.z); tmp[q*4+3] = f2bf(v.w);
      }
      int b0 = sr * 64 + skh * 2;
      int sw = (sr & 7) << 4;
      *(us8*)((char*)lA + ((b0)      ^ sw)) = *(us8*)tmp;
      *(us8*)((char*)lA + ((b0 + 16) ^ sw)) = *(us8*)(tmp + 8);
    }
    if (BCOL == 0) {
      const float* src = B + (long long)(n0 + sr) * ldb + k0 + skh;
      unsigned short tmp[16];
      #pragma unroll
      for (int q = 0; q < 4; ++q) {
        float4 v = *(const float4*)(src + q * 4);
        tmp[q*4+0] = f2bf(v.x); tmp[q*4+1] = f2bf(v.y);
        tmp[q*4+2] = f2bf(v.z); tmp[q*4+3] = f2bf(v.w);
      }
      int b0 = sr * 64 + skh * 2;
      int sw = (sr & 7) << 4;
      *(us8*)((char*)lB + ((b0)      ^ sw)) = *(us8*)tmp;
      *(us8*)((char*)lB + ((b0 + 16) ^ sw)) = *(us8*)(tmp + 8);
    } else {
      float va[4][4];
      #pragma unroll
      for (int kk = 0; kk < 4; ++kk) {
        float4 v = *(const float4*)(B + (long long)(k0 + ck4 + kk) * ldb + n0 + cn4);
        va[kk][0] = v.x; va[kk][1] = v.y; va[kk][2] = v.z; va[kk][3] = v.w;
      }
      #pragma unroll
      for (int nn = 0; nn < 4; ++nn) {
        us4 w;
        w[0] = f2bf(va[0][nn]); w[1] = f2bf(va[1][nn]);
        w[2] = f2bf(va[2][nn]); w[3] = f2bf(va[3][nn]);
        int row = cn4 + nn;
        int b0  = row * 64 + ck4 * 2;
        *(us4*)((char*)lB + (b0 ^ ((row & 7) << 4))) = w;
      }
    }
    __syncthreads();

    v8bf af[4], bf[4];
    #pragma unroll
    for (int i = 0; i < 4; ++i) {
      int r  = wr * 64 + i * 16 + lrow;
      int b0 = (r * 64 + lk * 16) ^ ((r & 7) << 4);
      af[i] = __builtin_bit_cast(v8bf, *(const us8*)((const char*)lA + b0));
    }
    #pragma unroll
    for (int j = 0; j < 4; ++j) {
      int r  = wc * 64 + j * 16 + lrow;
      int b0 = (r * 64 + lk * 16) ^ ((r & 7) << 4);
      bf[j] = __builtin_bit_cast(v8bf, *(const us8*)((const char*)lB + b0));
    }
    #pragma unroll
    for (int i = 0; i < 4; ++i)
      #pragma unroll
      for (int j = 0; j < 4; ++j)
        acc[i][j] = __builtin_amdgcn_mfma_f32_16x16x32_bf16(af[i], bf[j], acc[i][j], 0, 0, 0);
  }

  #pragma unroll
  for (int i = 0; i < 4; ++i) {
    #pragma unroll
    for (int j = 0; j < 4; ++j) {
      int gm = m0 + wr * 64 + i * 16 + lk * 4;
      int gn = n0 + wc * 64 + j * 16 + lrow;
      if (CT == 0) {
        #pragma unroll
        for (int r = 0; r < 4; ++r)
          C[(long long)(gm + r) * ldc + gn] = acc[i][j][r];
      } else {
        *(v4f*)&C[(long long)gn * ldc + gm] = acc[i][j];
      }
    }
  }
}

// ---------------------------------------------------------------------------
// Generic 64x64x16 fp32 tiled GEMM. ACT 1: softplus(acc + bias[m]) epilogue.
// ---------------------------------------------------------------------------
template<int AMODE, int BMODE, int ACT>
__global__ __launch_bounds__(256) void gemm64(
    const float* __restrict__ A, const float* __restrict__ B,
    float* __restrict__ C, const float* __restrict__ bias,
    int M, int N, int K, int lda, int ldb, int ldc,
    long long sA, long long sB_, long long sC)
{
  constexpr int BM = 64, BN = 64, BK = 16;
  __shared__ float As[BK][BM + 4];
  __shared__ float Bs[BK][BN + 4];

  const int tid = threadIdx.x;
  const int bz  = blockIdx.z;
  A += sA  * bz;
  B += sB_ * bz;
  C += sC  * bz;

  const int m0 = blockIdx.y * BM;
  const int n0 = blockIdx.x * BN;
  const int tx = tid & 15;
  const int ty = tid >> 4;

  float acc[4][4] = {};

  for (int k0 = 0; k0 < K; k0 += BK) {
    #pragma unroll
    for (int i = 0; i < 4; ++i) {
      int idx = tid + i * 256;
      int m, k;
      if (AMODE == 0) { k = idx & (BK - 1); m = idx >> 4; }
      else            { m = idx & (BM - 1); k = idx >> 6; }
      int gm = m0 + m;
      float v = 0.f;
      if (gm < M)
        v = (AMODE == 0) ? A[(long long)gm * lda + (k0 + k)]
                         : A[(long long)(k0 + k) * lda + gm];
      As[k][m] = v;
    }
    #pragma unroll
    for (int i = 0; i < 4; ++i) {
      int idx = tid + i * 256;
      int n, k;
      if (BMODE == 0) { k = idx & (BK - 1); n = idx >> 4; }
      else            { n = idx & (BN - 1); k = idx >> 6; }
      int gn = n0 + n;
      float v = (BMODE == 0) ? B[(long long)gn * ldb + (k0 + k)]
                             : B[(long long)(k0 + k) * ldb + gn];
      Bs[k][n] = v;
    }
    __syncthreads();

    #pragma unroll
    for (int k = 0; k < BK; ++k) {
      float4 av = *(const float4*)&As[k][ty * 4];
      float4 bv = *(const float4*)&Bs[k][tx * 4];
      float a_[4] = {av.x, av.y, av.z, av.w};
      float b_[4] = {bv.x, bv.y, bv.z, bv.w};
      #pragma unroll
      for (int i = 0; i < 4; ++i)
        #pragma unroll
        for (int j = 0; j < 4; ++j)
          acc[i][j] = fmaf(a_[i], b_[j], acc[i][j]);
    }
    __syncthreads();
  }

  #pragma unroll
  for (int i = 0; i < 4; ++i) {
    int gm = m0 + ty * 4 + i;
    if (gm < M) {
      float bv = (ACT == 1) ? bias[gm] : 0.f;
      #pragma unroll
      for (int j = 0; j < 4; ++j) {
        float v = acc[i][j];
        if (ACT == 1) {
          v += bv;
          v = (v > 20.f) ? v : log1pf(__expf(v));
        }
        C[(long long)gm * ldc + n0 + tx * 4 + j] = v;
      }
    }
  }
}

// ---------------------------------------------------------------------------
// Split-K partials GEMM for K3 (M=96, K=2048 -> KC_ chunks). No atomics:
// each (kc, b) writes its own slab part[(kc*B_+b)*96 + r][l].
// grid (N/64, 2*KC_, B); blockIdx.y = mblk + 2*kc.
// ---------------------------------------------------------------------------
__global__ __launch_bounds__(256) void gemm64_p(
    const float* __restrict__ A, const float* __restrict__ B,
    float* __restrict__ part,
    int M, int N, int K, int lda, int ldb,
    long long sB_)
{
  constexpr int BM = 64, BN = 64, BK = 16;
  __shared__ float As[BK][BM + 4];
  __shared__ float Bs[BK][BN + 4];

  const int tid = threadIdx.x;
  const int bz  = blockIdx.z;
  B += sB_ * bz;

  const int m0  = (blockIdx.y & 1) * BM;
  const int kc  = blockIdx.y >> 1;
  const int n0  = blockIdx.x * BN;
  const int kend = (kc + 1) * (K / KC_);
  const int tx = tid & 15;
  const int ty = tid >> 4;

  float* Cp = part + ((size_t)(kc * B_ + bz) * 96) * (size_t)L_;

  float acc[4][4] = {};

  for (int k0 = kc * (K / KC_); k0 < kend; k0 += BK) {
    #pragma unroll
    for (int i = 0; i < 4; ++i) {
      int idx = tid + i * 256;
      int k = idx & (BK - 1), m = idx >> 4;
      int gm = m0 + m;
      As[k][m] = (gm < M) ? A[(long long)gm * lda + (k0 + k)] : 0.f;
    }
    #pragma unroll
    for (int i = 0; i < 4; ++i) {
      int idx = tid + i * 256;
      int n = idx & (BN - 1), k = idx >> 6;
      Bs[k][n] = B[(long long)(k0 + k) * ldb + (n0 + n)];
    }
    __syncthreads();

    #pragma unroll
    for (int k = 0; k < BK; ++k) {
      float4 av = *(const float4*)&As[k][ty * 4];
      float4 bv = *(const float4*)&Bs[k][tx * 4];
      float a_[4] = {av.x, av.y, av.z, av.w};
      float b_[4] = {bv.x, bv.y, bv.z, bv.w};
      #pragma unroll
      for (int i = 0; i < 4; ++i)
        #pragma unroll
        for (int j = 0; j < 4; ++j)
          acc[i][j] = fmaf(a_[i], b_[j], acc[i][j]);
    }
    __syncthreads();
  }

  #pragma unroll
  for (int i = 0; i < 4; ++i) {
    int gm = m0 + ty * 4 + i;
    if (gm < M)
      *(float4*)&Cp[(size_t)gm * L_ + n0 + tx * 4] = *(float4*)&acc[i][0];
  }
}

// reduce KC_ partial slabs -> x_dbl. One float4 per thread.
__global__ __launch_bounds__(256) void k3_reduce(
    const float* __restrict__ part, float* __restrict__ xdbl)
{
  int i   = blockIdx.x * 256 + threadIdx.x;     // [0, B*96*L/4)
  int l4  = (i & (L_ / 4 - 1)) << 2;
  int row = i >> 9;                              // b*96 + r
  float4 a = make_float4(0.f, 0.f, 0.f, 0.f);
  #pragma unroll
  for (int kc = 0; kc < KC_; ++kc) {
    float4 v = *(const float4*)&part[((size_t)(kc * B_ * 96 + row)) * L_ + l4];
    a.x += v.x; a.y += v.y; a.z += v.z; a.w += v.w;
  }
  *(float4*)&xdbl[(size_t)row * L_ + l4] = a;
}

// ---------------------------------------------------------------------------
// Depthwise causal conv (k=4) + bias + SiLU (round-1 exact).
// ---------------------------------------------------------------------------
__global__ __launch_bounds__(256) void conv_silu_kernel(
    const float* __restrict__ xz, const float* __restrict__ cw,
    const float* __restrict__ cb, float* __restrict__ xc)
{
  int idx = blockIdx.x * 256 + threadIdx.x;
  int l4  = (idx & (L_ / 4 - 1)) << 2;
  int row = idx >> 9;
  int d   = row & (DI_ - 1);
  int b   = row >> 11;

  const float* in = xz + ((size_t)b * 2 * DI_ + d) * L_;
  float w0 = cw[d * 4 + 0], w1 = cw[d * 4 + 1];
  float w2 = cw[d * 4 + 2], w3 = cw[d * 4 + 3];
  float bias = cb[d];

  float o[4];
  #pragma unroll
  for (int j = 0; j < 4; ++j) {
    int l = l4 + j;
    float acc = bias + in[l] * w3;
    if (l >= 1) acc += in[l - 1] * w2;
    if (l >= 2) acc += in[l - 2] * w1;
    if (l >= 3) acc += in[l - 3] * w0;
    float sig = 1.f / (1.f + __expf(-acc));
    o[j] = acc * sig;
  }
  *(float4*)&xc[(size_t)row * L_ + l4] = *(float4*)o;
}

// ---------------------------------------------------------------------------
// Selective scan v3 (round-7 exact): dv pre-softplus'd, 8-step batches,
// T14 register prefetch, DPP reduce -> lane 15.
// ---------------------------------------------------------------------------
__global__ __launch_bounds__(256) void scan_kernel(
    float* __restrict__ xz, const float* __restrict__ xconv,
    const float* __restrict__ x_dbl, const float* __restrict__ A_log,
    const float* __restrict__ Dw)
{
  const int tid = threadIdx.x;
  const int g   = tid >> 4;
  const int n   = tid & 15;
  const int gid = blockIdx.x * 16 + g;
  const int b   = gid >> 11;
  const int d   = gid & (DI_ - 1);
  const int bb  = blockIdx.x >> 7;
  const int d0  = (blockIdx.x << 4) & (DI_ - 1);

  const float An = -expf(A_log[d * DS_ + n]);
  const float Dd = Dw[d];

  float*       xrow  = xz + ((size_t)b * 2 * DI_ + d) * L_;
  const float* Bbase = x_dbl + ((size_t)b * 96 + DTR_) * L_;
  const float* Cbase = x_dbl + ((size_t)b * 96 + DTR_ + DS_) * L_;

  const float* drow0 = xz    + ((size_t)bb * 2 * DI_ + d0) * L_;
  const float* zrow0 = xz    + ((size_t)bb * 2 * DI_ + DI_ + d0) * L_;
  const float* xrow0 = xconv + ((size_t)bb * DI_ + d0) * L_;

  __shared__ float sD[16][68], sX[16][68], sZ[16][68];
  __shared__ float sB[16][68], sC[16][68];

  const int sr = tid >> 4, sc4 = (tid & 15) * 4;
  const size_t soff = (size_t)sr * L_ + sc4;

  float4 rD = *(const float4*)&drow0[soff];
  float4 rX = *(const float4*)&xrow0[soff];
  float4 rZ = *(const float4*)&zrow0[soff];
  float4 rB = *(const float4*)&Bbase[soff];
  float4 rC = *(const float4*)&Cbase[soff];

  float h = 0.f;
  for (int l0 = 0; l0 < L_; l0 += 64) {
    __syncthreads();
    *(float4*)&sD[sr][sc4] = rD;
    *(float4*)&sX[sr][sc4] = rX;
    *(float4*)&sZ[sr][sc4] = rZ;
    *(float4*)&sB[sr][sc4] = rB;
    *(float4*)&sC[sr][sc4] = rC;
    __syncthreads();

    if (l0 + 64 < L_) {
      rD = *(const float4*)&drow0[soff + l0 + 64];
      rX = *(const float4*)&xrow0[soff + l0 + 64];
      rZ = *(const float4*)&zrow0[soff + l0 + 64];
      rB = *(const float4*)&Bbase[soff + l0 + 64];
      rC = *(const float4*)&Cbase[soff + l0 + 64];
    }

    #pragma unroll
    for (int l8 = 0; l8 < 64; l8 += 8) {
      float dv[8], xv[8], Bn[8], Cn[8];
      *(float4*)&dv[0] = *(const float4*)&sD[g][l8];
      *(float4*)&dv[4] = *(const float4*)&sD[g][l8 + 4];
      *(float4*)&xv[0] = *(const float4*)&sX[g][l8];
      *(float4*)&xv[4] = *(const float4*)&sX[g][l8 + 4];
      *(float4*)&Bn[0] = *(const float4*)&sB[n][l8];
      *(float4*)&Bn[4] = *(const float4*)&sB[n][l8 + 4];
      *(float4*)&Cn[0] = *(const float4*)&sC[n][l8];
      *(float4*)&Cn[4] = *(const float4*)&sC[n][l8 + 4];

      float dA[8], dBu[8];
      #pragma unroll
      for (int j = 0; j < 8; ++j) {
        dA[j]  = __expf(dv[j] * An);
        dBu[j] = dv[j] * Bn[j] * xv[j];
      }
      float p[8];
      #pragma unroll
      for (int j = 0; j < 8; ++j) {
        h = fmaf(dA[j], h, dBu[j]);
        p[j] = h * Cn[j];
      }
      #pragma unroll
      for (int j = 0; j < 8; ++j) p[j] = dpp_shr_add<0x111>(p[j]);
      #pragma unroll
      for (int j = 0; j < 8; ++j) p[j] = dpp_shr_add<0x112>(p[j]);
      #pragma unroll
      for (int j = 0; j < 8; ++j) p[j] = dpp_shr_add<0x114>(p[j]);
      #pragma unroll
      for (int j = 0; j < 8; ++j) p[j] = dpp_shr_add<0x118>(p[j]);

      if (n == 15) {
        float zv[8], o[8];
        *(float4*)&zv[0] = *(const float4*)&sZ[g][l8];
        *(float4*)&zv[4] = *(const float4*)&sZ[g][l8 + 4];
        #pragma unroll
        for (int j = 0; j < 8; ++j) {
          float y   = p[j] + xv[j] * Dd;
          float sig = 1.f / (1.f + __expf(-zv[j]));
          o[j] = y * zv[j] * sig;
        }
        *(float4*)&xrow[l0 + l8]     = *(const float4*)&o[0];
        *(float4*)&xrow[l0 + l8 + 4] = *(const float4*)&o[4];
      }
    }
  }
}

// ---------------------------------------------------------------------------
extern "C" void kernel_launch(void* const* d_in, const int* in_sizes, int n_in,
                              void* d_out, int out_size, void* d_ws, size_t ws_size,
                              hipStream_t stream)
{
  const float* hs   = (const float*)d_in[0];
  const float* w1   = (const float*)d_in[1];
  const float* cw   = (const float*)d_in[2];
  const float* cb   = (const float*)d_in[3];
  const float* xpw  = (const float*)d_in[4];
  const float* dtw  = (const float*)d_in[5];
  const float* dtbp = (const float*)d_in[6];
  const float* Alog = (const float*)d_in[7];
  const float* Dw   = (const float*)d_in[8];
  const float* wo   = (const float*)d_in[9];
  float* out = (float*)d_out;

  char* ws = (char*)d_ws;
  float* xz    = (float*)ws;                                     // B*2DI*L
  float* xconv = (float*)(ws + (size_t)B_ * 2 * DI_ * L_ * 4);   // B*DI*L
  float* xdbl  = (float*)(ws + (size_t)B_ * 2 * DI_ * L_ * 4
                             + (size_t)B_ * DI_ * L_ * 4);       // B*96*L

  // K3 partials live in xz's b=0 x-half (rows 0..1535): dead between K2 and K4.
  float* part = xz;

  // K1 (bf16 MFMA): xz[b][e][l] = sum_d hs[b][l][d] * w1[e][d]
  {
    dim3 g(L_ / 128, (2 * DI_) / 128, B_);
    gemm_mfma<0, 0><<<g, 256, 0, stream>>>(w1, hs, xz,
        2 * DI_, L_, DM_, DM_, DM_, L_,
        0LL, (long long)L_ * DM_, (long long)2 * DI_ * L_);
  }

  // K2: depthwise conv + SiLU
  conv_silu_kernel<<<dim3(B_ * DI_ * L_ / 4 / 256), 256, 0, stream>>>(xz, cw, cb, xconv);

  // K3a (split-K partials, no atomics): part[kc][b][r][l]
  {
    dim3 g(L_ / 64, 2 * KC_, B_);
    gemm64_p<<<g, 256, 0, stream>>>(xpw, xconv, part,
        96, L_, DI_, DI_, L_,
        (long long)DI_ * L_);
  }
  // K3b: x_dbl = sum_kc part[kc]
  k3_reduce<<<dim3(B_ * 96 * L_ / 4 / 256), 256, 0, stream>>>(part, xdbl);

  // K4: dv[b][d][l] = softplus(sum_r dtw[d][r]*x_dbl[b][r][l] + dtb[d])
  {
    dim3 g(L_ / 64, DI_ / 64, B_);
    gemm64<0, 1, 1><<<g, 256, 0, stream>>>(dtw, xdbl, xz, dtbp,
        DI_, L_, DTR_, DTR_, L_, L_,
        0LL, (long long)96 * L_, (long long)2 * DI_ * L_);
  }

  // K5: selective scan v3
  scan_kernel<<<dim3(B_ * DI_ / 16), 256, 0, stream>>>(xz, xconv, xdbl, Alog, Dw);

  // K6 (bf16 MFMA, M=o): out[b][l][o] = sum_d y[b][d][l] * wo[o][d]
  {
    dim3 g(L_ / 128, DM_ / 128, B_);
    gemm_mfma<1, 1><<<g, 256, 0, stream>>>(wo, xz, out,
        DM_, L_, DI_, DI_, L_, DM_,
        0LL, (long long)2 * DI_ * L_, (long long)L_ * DM_);
  }
}